// Round 2
// baseline (7825.836 us; speedup 1.0000x reference)
//
#include <hip/hip_runtime.h>

#define D 128

// ---------------- threefry2x32 (JAX-compatible, 20 rounds) ----------------
__device__ __forceinline__ unsigned rotl32(unsigned v, int r) {
  return (v << r) | (v >> (32 - r));
}

__device__ __forceinline__ void threefry2x32(unsigned k0, unsigned k1,
                                             unsigned x0, unsigned x1,
                                             unsigned &o0, unsigned &o1) {
  unsigned ks2 = k0 ^ k1 ^ 0x1BD11BDAu;
  unsigned v0 = x0 + k0;
  unsigned v1 = x1 + k1;
  v0 += v1; v1 = rotl32(v1, 13); v1 ^= v0;
  v0 += v1; v1 = rotl32(v1, 15); v1 ^= v0;
  v0 += v1; v1 = rotl32(v1, 26); v1 ^= v0;
  v0 += v1; v1 = rotl32(v1, 6);  v1 ^= v0;
  v0 += k1; v1 += ks2 + 1u;
  v0 += v1; v1 = rotl32(v1, 17); v1 ^= v0;
  v0 += v1; v1 = rotl32(v1, 29); v1 ^= v0;
  v0 += v1; v1 = rotl32(v1, 16); v1 ^= v0;
  v0 += v1; v1 = rotl32(v1, 24); v1 ^= v0;
  v0 += ks2; v1 += k0 + 2u;
  v0 += v1; v1 = rotl32(v1, 13); v1 ^= v0;
  v0 += v1; v1 = rotl32(v1, 15); v1 ^= v0;
  v0 += v1; v1 = rotl32(v1, 26); v1 ^= v0;
  v0 += v1; v1 = rotl32(v1, 6);  v1 ^= v0;
  v0 += k0; v1 += k1 + 3u;
  v0 += v1; v1 = rotl32(v1, 17); v1 ^= v0;
  v0 += v1; v1 = rotl32(v1, 29); v1 ^= v0;
  v0 += v1; v1 = rotl32(v1, 16); v1 ^= v0;
  v0 += v1; v1 = rotl32(v1, 24); v1 ^= v0;
  v0 += k1; v1 += ks2 + 4u;
  v0 += v1; v1 = rotl32(v1, 13); v1 ^= v0;
  v0 += v1; v1 = rotl32(v1, 15); v1 ^= v0;
  v0 += v1; v1 = rotl32(v1, 26); v1 ^= v0;
  v0 += v1; v1 = rotl32(v1, 6);  v1 ^= v0;
  v0 += ks2; v1 += k0 + 5u;
  o0 = v0; o1 = v1;
}

// ---------------- order-preserving float<->uint for atomic max ----------------
__device__ __forceinline__ unsigned fmap(float f) {
  unsigned u = __float_as_uint(f);
  return (u & 0x80000000u) ? ~u : (u | 0x80000000u);
}
__device__ __forceinline__ float funmap(unsigned m) {
  if (m == 0u) return 0.0f;  // no incoming edges -> segment_max = -inf -> 0
  return (m & 0x80000000u) ? __uint_as_float(m & 0x7FFFFFFFu)
                           : __uint_as_float(~m);
}

// ---------------- per-edge scatter max ----------------
__global__ __launch_bounds__(256) void scatter_max_kernel(
    const float* __restrict__ x, const int* __restrict__ src,
    const int* __restrict__ dst, unsigned* __restrict__ agg, int nEdges) {
  int e = blockIdx.x * 8 + (threadIdx.x >> 5);
  if (e >= nEdges) return;
  int lane = threadIdx.x & 31;
  int s = src[e];
  int d = dst[e];
  const float4* xr = reinterpret_cast<const float4*>(x + (size_t)s * D);
  float4 v = xr[lane];
  unsigned* ar = agg + (size_t)d * D + lane * 4;
  atomicMax(ar + 0, fmap(v.x));
  atomicMax(ar + 1, fmap(v.y));
  atomicMax(ar + 2, fmap(v.z));
  atomicMax(ar + 3, fmap(v.w));
}

// ---------------- fused: out = decode(agg) @ Wl + x @ Wr + b (+ELU +dropout) ----------------
// mode 0: ELU + dropout with key k1; mode 1: ELU + dropout with key k2; mode 2: plain.
__global__ __launch_bounds__(256) void fused_layer_kernel(
    const unsigned* __restrict__ agg, const float* __restrict__ x,
    const float* __restrict__ Wl, const float* __restrict__ Wr,
    const float* __restrict__ bias, float* __restrict__ out,
    int nRows, int mode) {
  __shared__ float sX[16][256];        // [row][ agg(0..127) | x(128..255) ]
  __shared__ float sW[2][32][128];     // [half][k][c] chunk
  __shared__ float sAcc[16][128];      // half-1 partials

  const int tid = threadIdx.x;
  const int c = tid & 127;
  const int h = tid >> 7;
  const int row0 = blockIdx.x * 16;

  for (int i = 0; i < 16; ++i) {
    int n = row0 + i;
    float v = 0.0f;
    if (n < nRows) {
      if (tid < 128)
        v = funmap(agg[(size_t)n * D + tid]);
      else
        v = x[(size_t)n * D + (tid - 128)];
    }
    sX[i][tid] = v;
  }

  float acc[16];
#pragma unroll
  for (int r = 0; r < 16; ++r) acc[r] = 0.0f;

  const float* Wsrc[2] = {Wl, Wr};

  for (int kb = 0; kb < 128; kb += 32) {
    __syncthreads();
    for (int i = 0; i < 32; ++i) {
      int idx = i * 256 + tid;
      int hh = idx >> 12;
      int k = (idx >> 7) & 31;
      int cc = idx & 127;
      (&sW[0][0][0])[idx] = Wsrc[hh][(size_t)(kb + k) * D + cc];
    }
    __syncthreads();

    float w[32];
#pragma unroll
    for (int k = 0; k < 32; ++k) w[k] = sW[h][k][c];

    const int xbase4 = (h * 128 + kb) >> 2;
#pragma unroll
    for (int r = 0; r < 16; ++r) {
      const float4* row4 = reinterpret_cast<const float4*>(&sX[r][0]);
#pragma unroll
      for (int k4 = 0; k4 < 8; ++k4) {
        float4 xv = row4[xbase4 + k4];
        acc[r] += xv.x * w[k4 * 4 + 0];
        acc[r] += xv.y * w[k4 * 4 + 1];
        acc[r] += xv.z * w[k4 * 4 + 2];
        acc[r] += xv.w * w[k4 * 4 + 3];
      }
    }
  }

  __syncthreads();
  if (h == 1) {
#pragma unroll
    for (int r = 0; r < 16; ++r) sAcc[r][c] = acc[r];
  }
  __syncthreads();

  if (h == 0) {
    // --- JAX partitionable threefry (jax_threefry_partitionable=True, JAX >= 0.4.36) ---
    // split(key(42)): subkey i = full block output (o0,o1) at counter (0, i)
    unsigned k1a, k1b, k2a, k2b;
    threefry2x32(0u, 42u, 0u, 0u, k1a, k1b);
    threefry2x32(0u, 42u, 0u, 1u, k2a, k2b);
    unsigned kk0 = (mode == 0) ? k1a : k2a;
    unsigned kk1 = (mode == 0) ? k1b : k2b;

    float bc = bias[c];
#pragma unroll
    for (int r = 0; r < 16; ++r) {
      int n = row0 + r;
      if (n >= nRows) break;
      float v = acc[r] + sAcc[r][c] + bc;
      if (mode < 2) {
        // ELU (alpha=1)
        v = (v > 0.0f) ? v : expm1f(v);
        // random_bits(32) partitionable: block at counter (0, j), bits = o0 ^ o1
        unsigned j = (unsigned)n * D + c;
        unsigned y0, y1;
        threefry2x32(kk0, kk1, 0u, j, y0, y1);
        unsigned bits = y0 ^ y1;
        float u = __uint_as_float((bits >> 9) | 0x3F800000u) - 1.0f;
        v = (u < 0.8f) ? (v / 0.8f) : 0.0f;
      }
      out[(size_t)n * D + c] = v;
    }
  }
}

extern "C" void kernel_launch(void* const* d_in, const int* in_sizes, int n_in,
                              void* d_out, int out_size, void* d_ws, size_t ws_size,
                              hipStream_t stream) {
  const float* feat = (const float*)d_in[0];
  const int* ei = (const int*)d_in[1];
  const float* Wl0 = (const float*)d_in[2];
  const float* Wr0 = (const float*)d_in[3];
  const float* b0 = (const float*)d_in[4];
  const float* Wl1 = (const float*)d_in[5];
  const float* Wr1 = (const float*)d_in[6];
  const float* b1 = (const float*)d_in[7];
  const float* Wl2 = (const float*)d_in[8];
  const float* Wr2 = (const float*)d_in[9];
  const float* b2 = (const float*)d_in[10];

  const int N = in_sizes[0] / D;   // 100000
  const int E = in_sizes[1] / 2;   // 1600000
  const int* src = ei;
  const int* dst = ei + E;

  const size_t featBytes = (size_t)N * D * sizeof(float);
  unsigned* agg = (unsigned*)d_ws;
  float* x1 = (float*)((char*)d_ws + featBytes);
  float* out = (float*)d_out;

  dim3 sblk(256), sgrd((E + 7) / 8);
  dim3 gblk(256), ggrd((N + 15) / 16);

  // ---- layer 0 ----
  hipMemsetAsync(agg, 0, featBytes, stream);
  scatter_max_kernel<<<sgrd, sblk, 0, stream>>>(feat, src, dst, agg, E);
  fused_layer_kernel<<<ggrd, gblk, 0, stream>>>(agg, feat, Wl0, Wr0, b0, x1, N, 0);

  // ---- layer 1 ----
  hipMemsetAsync(agg, 0, featBytes, stream);
  scatter_max_kernel<<<sgrd, sblk, 0, stream>>>(x1, src, dst, agg, E);
  fused_layer_kernel<<<ggrd, gblk, 0, stream>>>(agg, x1, Wl1, Wr1, b1, out, N, 1);

  // ---- layer 2 ----
  hipMemsetAsync(agg, 0, featBytes, stream);
  scatter_max_kernel<<<sgrd, sblk, 0, stream>>>(out, src, dst, agg, E);
  fused_layer_kernel<<<ggrd, gblk, 0, stream>>>(agg, out, Wl2, Wr2, b2, out, N, 2);
}

// Round 3
// 2015.819 us; speedup vs baseline: 3.8822x; 3.8822x over previous
//
#include <hip/hip_runtime.h>
#include <math.h>

#define D 128
#define CHUNK 1024

// ---------------- threefry2x32 (JAX-compatible, 20 rounds) ----------------
__device__ __forceinline__ unsigned rotl32(unsigned v, int r) {
  return (v << r) | (v >> (32 - r));
}

__device__ __forceinline__ void threefry2x32(unsigned k0, unsigned k1,
                                             unsigned x0, unsigned x1,
                                             unsigned &o0, unsigned &o1) {
  unsigned ks2 = k0 ^ k1 ^ 0x1BD11BDAu;
  unsigned v0 = x0 + k0;
  unsigned v1 = x1 + k1;
  v0 += v1; v1 = rotl32(v1, 13); v1 ^= v0;
  v0 += v1; v1 = rotl32(v1, 15); v1 ^= v0;
  v0 += v1; v1 = rotl32(v1, 26); v1 ^= v0;
  v0 += v1; v1 = rotl32(v1, 6);  v1 ^= v0;
  v0 += k1; v1 += ks2 + 1u;
  v0 += v1; v1 = rotl32(v1, 17); v1 ^= v0;
  v0 += v1; v1 = rotl32(v1, 29); v1 ^= v0;
  v0 += v1; v1 = rotl32(v1, 16); v1 ^= v0;
  v0 += v1; v1 = rotl32(v1, 24); v1 ^= v0;
  v0 += ks2; v1 += k0 + 2u;
  v0 += v1; v1 = rotl32(v1, 13); v1 ^= v0;
  v0 += v1; v1 = rotl32(v1, 15); v1 ^= v0;
  v0 += v1; v1 = rotl32(v1, 26); v1 ^= v0;
  v0 += v1; v1 = rotl32(v1, 6);  v1 ^= v0;
  v0 += k0; v1 += k1 + 3u;
  v0 += v1; v1 = rotl32(v1, 17); v1 ^= v0;
  v0 += v1; v1 = rotl32(v1, 29); v1 ^= v0;
  v0 += v1; v1 = rotl32(v1, 16); v1 ^= v0;
  v0 += v1; v1 = rotl32(v1, 24); v1 ^= v0;
  v0 += k1; v1 += ks2 + 4u;
  v0 += v1; v1 = rotl32(v1, 13); v1 ^= v0;
  v0 += v1; v1 = rotl32(v1, 15); v1 ^= v0;
  v0 += v1; v1 = rotl32(v1, 26); v1 ^= v0;
  v0 += v1; v1 = rotl32(v1, 6);  v1 ^= v0;
  v0 += ks2; v1 += k0 + 5u;
  o0 = v0; o1 = v1;
}

// ================= CSR build =================
__global__ __launch_bounds__(256) void hist_kernel(
    const int* __restrict__ dst, int* __restrict__ counts, int nEdges) {
  int e = blockIdx.x * 256 + threadIdx.x;
  if (e < nEdges) atomicAdd(&counts[dst[e]], 1);
}

__global__ __launch_bounds__(256) void reduce_chunk_kernel(
    const int* __restrict__ counts, int* __restrict__ blockSums, int nNodes) {
  __shared__ int s[256];
  int t = threadIdx.x;
  int base = blockIdx.x * CHUNK + t * 4;
  int sum = 0;
#pragma unroll
  for (int i = 0; i < 4; ++i)
    if (base + i < nNodes) sum += counts[base + i];
  s[t] = sum;
  __syncthreads();
  for (int off = 128; off > 0; off >>= 1) {
    if (t < off) s[t] += s[t + off];
    __syncthreads();
  }
  if (t == 0) blockSums[blockIdx.x] = s[0];
}

__global__ void scan_block_sums_kernel(int* blockSums, int nChunks) {
  if (threadIdx.x == 0 && blockIdx.x == 0) {
    int run = 0;
    for (int i = 0; i < nChunks; ++i) {
      int v = blockSums[i];
      blockSums[i] = run;
      run += v;
    }
  }
}

__global__ __launch_bounds__(256) void scan_chunk_kernel(
    const int* __restrict__ counts, const int* __restrict__ blockOffs,
    int* __restrict__ rowStart, int* __restrict__ cursor, int nNodes) {
  __shared__ int sSum[256];
  int t = threadIdx.x;
  int base = blockIdx.x * CHUNK + t * 4;
  int c0 = 0, c1 = 0, c2 = 0, c3 = 0;
  if (base + 0 < nNodes) c0 = counts[base + 0];
  if (base + 1 < nNodes) c1 = counts[base + 1];
  if (base + 2 < nNodes) c2 = counts[base + 2];
  if (base + 3 < nNodes) c3 = counts[base + 3];
  int local = c0 + c1 + c2 + c3;
  sSum[t] = local;
  __syncthreads();
  // Hillis-Steele inclusive scan over 256 thread-sums
  for (int off = 1; off < 256; off <<= 1) {
    int v = (t >= off) ? sSum[t - off] : 0;
    __syncthreads();
    sSum[t] += v;
    __syncthreads();
  }
  int excl = blockOffs[blockIdx.x] + sSum[t] - local;
  int p0 = excl, p1 = p0 + c0, p2 = p1 + c1, p3 = p2 + c2;
  if (base + 0 < nNodes) { rowStart[base + 0] = p0; cursor[base + 0] = p0;
                           if (base + 0 == nNodes - 1) rowStart[nNodes] = p1; }
  if (base + 1 < nNodes) { rowStart[base + 1] = p1; cursor[base + 1] = p1;
                           if (base + 1 == nNodes - 1) rowStart[nNodes] = p2; }
  if (base + 2 < nNodes) { rowStart[base + 2] = p2; cursor[base + 2] = p2;
                           if (base + 2 == nNodes - 1) rowStart[nNodes] = p3; }
  if (base + 3 < nNodes) { rowStart[base + 3] = p3; cursor[base + 3] = p3;
                           if (base + 3 == nNodes - 1) rowStart[nNodes] = p3 + c3; }
}

__global__ __launch_bounds__(256) void fill_csr_kernel(
    const int* __restrict__ src, const int* __restrict__ dst,
    int* __restrict__ cursor, int* __restrict__ csrSrc, int nEdges) {
  int e = blockIdx.x * 256 + threadIdx.x;
  if (e >= nEdges) return;
  int pos = atomicAdd(&cursor[dst[e]], 1);
  csrSrc[pos] = src[e];
}

// ================= gather-based segment max =================
// One wave (64 lanes) per destination node; lane handles 2 floats (float2).
__global__ __launch_bounds__(256) void gather_max_kernel(
    const float* __restrict__ x, const int* __restrict__ rowStart,
    const int* __restrict__ csrSrc, float* __restrict__ agg, int nNodes) {
  int n = blockIdx.x * 4 + (threadIdx.x >> 6);
  if (n >= nNodes) return;
  int lane = threadIdx.x & 63;
  int e0 = rowStart[n];
  int e1 = rowStart[n + 1];
  const float2* x2 = reinterpret_cast<const float2*>(x);
  float mx = -INFINITY, my = -INFINITY;
  int e = e0;
  for (; e + 1 < e1; e += 2) {
    int s0 = csrSrc[e];
    int s1 = csrSrc[e + 1];
    float2 v0 = x2[(size_t)s0 * 64 + lane];
    float2 v1 = x2[(size_t)s1 * 64 + lane];
    mx = fmaxf(mx, fmaxf(v0.x, v1.x));
    my = fmaxf(my, fmaxf(v0.y, v1.y));
  }
  if (e < e1) {
    int s0 = csrSrc[e];
    float2 v0 = x2[(size_t)s0 * 64 + lane];
    mx = fmaxf(mx, v0.x);
    my = fmaxf(my, v0.y);
  }
  if (e0 == e1) { mx = 0.0f; my = 0.0f; }  // isolated node -> 0
  reinterpret_cast<float2*>(agg)[(size_t)n * 64 + lane] = make_float2(mx, my);
}

// ---------------- fused: out = agg @ Wl + x @ Wr + b (+ELU +dropout) ----------------
// mode 0: ELU + dropout key k1; mode 1: ELU + dropout key k2; mode 2: plain.
// In-place safe: block stages its 16 rows of agg/x into LDS before writing out.
__global__ __launch_bounds__(256) void fused_layer_kernel(
    const float* __restrict__ agg, const float* __restrict__ x,
    const float* __restrict__ Wl, const float* __restrict__ Wr,
    const float* __restrict__ bias, float* __restrict__ out,
    int nRows, int mode) {
  __shared__ float sX[16][256];        // [row][ agg(0..127) | x(128..255) ]
  __shared__ float sW[2][32][128];     // [half][k][c] chunk
  __shared__ float sAcc[16][128];      // half-1 partials

  const int tid = threadIdx.x;
  const int c = tid & 127;
  const int h = tid >> 7;
  const int row0 = blockIdx.x * 16;

  for (int i = 0; i < 16; ++i) {
    int n = row0 + i;
    float v = 0.0f;
    if (n < nRows) {
      if (tid < 128)
        v = agg[(size_t)n * D + tid];
      else
        v = x[(size_t)n * D + (tid - 128)];
    }
    sX[i][tid] = v;
  }

  float acc[16];
#pragma unroll
  for (int r = 0; r < 16; ++r) acc[r] = 0.0f;

  const float* Wsrc[2] = {Wl, Wr};

  for (int kb = 0; kb < 128; kb += 32) {
    __syncthreads();
    for (int i = 0; i < 32; ++i) {
      int idx = i * 256 + tid;
      int hh = idx >> 12;
      int k = (idx >> 7) & 31;
      int cc = idx & 127;
      (&sW[0][0][0])[idx] = Wsrc[hh][(size_t)(kb + k) * D + cc];
    }
    __syncthreads();

    float w[32];
#pragma unroll
    for (int k = 0; k < 32; ++k) w[k] = sW[h][k][c];

    const int xbase4 = (h * 128 + kb) >> 2;
#pragma unroll
    for (int r = 0; r < 16; ++r) {
      const float4* row4 = reinterpret_cast<const float4*>(&sX[r][0]);
#pragma unroll
      for (int k4 = 0; k4 < 8; ++k4) {
        float4 xv = row4[xbase4 + k4];
        acc[r] += xv.x * w[k4 * 4 + 0];
        acc[r] += xv.y * w[k4 * 4 + 1];
        acc[r] += xv.z * w[k4 * 4 + 2];
        acc[r] += xv.w * w[k4 * 4 + 3];
      }
    }
  }

  __syncthreads();
  if (h == 1) {
#pragma unroll
    for (int r = 0; r < 16; ++r) sAcc[r][c] = acc[r];
  }
  __syncthreads();

  if (h == 0) {
    // JAX partitionable threefry: split(key(42)) -> subkey i = block at counter (0, i)
    unsigned k1a, k1b, k2a, k2b;
    threefry2x32(0u, 42u, 0u, 0u, k1a, k1b);
    threefry2x32(0u, 42u, 0u, 1u, k2a, k2b);
    unsigned kk0 = (mode == 0) ? k1a : k2a;
    unsigned kk1 = (mode == 0) ? k1b : k2b;

    float bc = bias[c];
#pragma unroll
    for (int r = 0; r < 16; ++r) {
      int n = row0 + r;
      if (n >= nRows) break;
      float v = acc[r] + sAcc[r][c] + bc;
      if (mode < 2) {
        v = (v > 0.0f) ? v : expm1f(v);  // ELU alpha=1
        unsigned j = (unsigned)n * D + c;
        unsigned y0, y1;
        threefry2x32(kk0, kk1, 0u, j, y0, y1);
        unsigned bits = y0 ^ y1;  // fold
        float u = __uint_as_float((bits >> 9) | 0x3F800000u) - 1.0f;
        v = (u < 0.8f) ? (v / 0.8f) : 0.0f;
      }
      out[(size_t)n * D + c] = v;
    }
  }
}

extern "C" void kernel_launch(void* const* d_in, const int* in_sizes, int n_in,
                              void* d_out, int out_size, void* d_ws, size_t ws_size,
                              hipStream_t stream) {
  const float* feat = (const float*)d_in[0];
  const int* ei = (const int*)d_in[1];
  const float* Wl0 = (const float*)d_in[2];
  const float* Wr0 = (const float*)d_in[3];
  const float* b0 = (const float*)d_in[4];
  const float* Wl1 = (const float*)d_in[5];
  const float* Wr1 = (const float*)d_in[6];
  const float* b1 = (const float*)d_in[7];
  const float* Wl2 = (const float*)d_in[8];
  const float* Wr2 = (const float*)d_in[9];
  const float* b2 = (const float*)d_in[10];

  const int N = in_sizes[0] / D;   // 100000
  const int E = in_sizes[1] / 2;   // 1600000
  const int* src = ei;
  const int* dst = ei + E;

  // ---- workspace layout (all within known-safe 102.4 MB) ----
  const size_t featBytes = (size_t)N * D * sizeof(float);     // 51.2 MB
  char* wsp = (char*)d_ws;
  float* x1       = (float*)wsp;                               // 51.2 MB (layers 1&2 reuse in-place)
  size_t off = featBytes;
  int* rowStart   = (int*)(wsp + off); off += ((size_t)(N + 1) * 4 + 511) & ~511ull;
  int* cursor     = (int*)(wsp + off); off += ((size_t)N * 4 + 511) & ~511ull;  // doubles as counts
  int* blockSums  = (int*)(wsp + off); off += 4096;
  int* csrSrc     = (int*)(wsp + off); off += (size_t)E * 4;   // 6.4 MB

  float* agg = (float*)d_out;  // agg lives in d_out between uses
  float* out = (float*)d_out;

  const int nChunks = (N + CHUNK - 1) / CHUNK;  // 98

  // ---- build CSR (per call; deterministic up to per-node permutation, max-invariant) ----
  hipMemsetAsync(cursor, 0, (size_t)N * 4, stream);
  hist_kernel<<<(E + 255) / 256, 256, 0, stream>>>(dst, cursor, E);
  reduce_chunk_kernel<<<nChunks, 256, 0, stream>>>(cursor, blockSums, N);
  scan_block_sums_kernel<<<1, 64, 0, stream>>>(blockSums, nChunks);
  scan_chunk_kernel<<<nChunks, 256, 0, stream>>>(cursor, blockSums, rowStart, cursor, N);
  fill_csr_kernel<<<(E + 255) / 256, 256, 0, stream>>>(src, dst, cursor, csrSrc, E);

  dim3 gblk(256);
  dim3 grdMax((N + 3) / 4);
  dim3 grdGemm((N + 15) / 16);

  // ---- layer 0 ----
  gather_max_kernel<<<grdMax, gblk, 0, stream>>>(feat, rowStart, csrSrc, agg, N);
  fused_layer_kernel<<<grdGemm, gblk, 0, stream>>>(agg, feat, Wl0, Wr0, b0, x1, N, 0);

  // ---- layer 1 (in-place on x1) ----
  gather_max_kernel<<<grdMax, gblk, 0, stream>>>(x1, rowStart, csrSrc, agg, N);
  fused_layer_kernel<<<grdGemm, gblk, 0, stream>>>(agg, x1, Wl1, Wr1, b1, x1, N, 1);

  // ---- layer 2 (agg in d_out, fused writes d_out in place) ----
  gather_max_kernel<<<grdMax, gblk, 0, stream>>>(x1, rowStart, csrSrc, agg, N);
  fused_layer_kernel<<<grdGemm, gblk, 0, stream>>>(agg, x1, Wl2, Wr2, b2, out, N, 2);
}

// Round 4
// 777.015 us; speedup vs baseline: 10.0717x; 2.5943x over previous
//
#include <hip/hip_runtime.h>
#include <math.h>

#define D 128
#define CHUNK 1024

typedef __attribute__((ext_vector_type(8))) short short8;
typedef __attribute__((ext_vector_type(4))) float floatx4;

// ---------------- threefry2x32 (JAX-compatible, 20 rounds) ----------------
__host__ __device__ __forceinline__ unsigned rotl32(unsigned v, int r) {
  return (v << r) | (v >> (32 - r));
}

__host__ __device__ __forceinline__ void threefry2x32(unsigned k0, unsigned k1,
                                                      unsigned x0, unsigned x1,
                                                      unsigned &o0, unsigned &o1) {
  unsigned ks2 = k0 ^ k1 ^ 0x1BD11BDAu;
  unsigned v0 = x0 + k0;
  unsigned v1 = x1 + k1;
  v0 += v1; v1 = rotl32(v1, 13); v1 ^= v0;
  v0 += v1; v1 = rotl32(v1, 15); v1 ^= v0;
  v0 += v1; v1 = rotl32(v1, 26); v1 ^= v0;
  v0 += v1; v1 = rotl32(v1, 6);  v1 ^= v0;
  v0 += k1; v1 += ks2 + 1u;
  v0 += v1; v1 = rotl32(v1, 17); v1 ^= v0;
  v0 += v1; v1 = rotl32(v1, 29); v1 ^= v0;
  v0 += v1; v1 = rotl32(v1, 16); v1 ^= v0;
  v0 += v1; v1 = rotl32(v1, 24); v1 ^= v0;
  v0 += ks2; v1 += k0 + 2u;
  v0 += v1; v1 = rotl32(v1, 13); v1 ^= v0;
  v0 += v1; v1 = rotl32(v1, 15); v1 ^= v0;
  v0 += v1; v1 = rotl32(v1, 26); v1 ^= v0;
  v0 += v1; v1 = rotl32(v1, 6);  v1 ^= v0;
  v0 += k0; v1 += k1 + 3u;
  v0 += v1; v1 = rotl32(v1, 17); v1 ^= v0;
  v0 += v1; v1 = rotl32(v1, 29); v1 ^= v0;
  v0 += v1; v1 = rotl32(v1, 16); v1 ^= v0;
  v0 += v1; v1 = rotl32(v1, 24); v1 ^= v0;
  v0 += k1; v1 += ks2 + 4u;
  v0 += v1; v1 = rotl32(v1, 13); v1 ^= v0;
  v0 += v1; v1 = rotl32(v1, 15); v1 ^= v0;
  v0 += v1; v1 = rotl32(v1, 26); v1 ^= v0;
  v0 += v1; v1 = rotl32(v1, 6);  v1 ^= v0;
  v0 += ks2; v1 += k0 + 5u;
  o0 = v0; o1 = v1;
}

// float -> bf16 (round to nearest even)
__device__ __forceinline__ unsigned short f2bf(float f) {
  unsigned u = __float_as_uint(f);
  unsigned r = u + 0x7FFFu + ((u >> 16) & 1u);
  return (unsigned short)(r >> 16);
}

// ================= CSR build =================
__global__ __launch_bounds__(256) void hist_kernel(
    const int* __restrict__ dst, int* __restrict__ counts, int nEdges) {
  int e = blockIdx.x * 256 + threadIdx.x;
  if (e < nEdges) atomicAdd(&counts[dst[e]], 1);
}

__global__ __launch_bounds__(256) void reduce_chunk_kernel(
    const int* __restrict__ counts, int* __restrict__ blockSums, int nNodes) {
  __shared__ int s[256];
  int t = threadIdx.x;
  int base = blockIdx.x * CHUNK + t * 4;
  int sum = 0;
#pragma unroll
  for (int i = 0; i < 4; ++i)
    if (base + i < nNodes) sum += counts[base + i];
  s[t] = sum;
  __syncthreads();
  for (int off = 128; off > 0; off >>= 1) {
    if (t < off) s[t] += s[t + off];
    __syncthreads();
  }
  if (t == 0) blockSums[blockIdx.x] = s[0];
}

__global__ void scan_block_sums_kernel(int* blockSums, int nChunks) {
  if (threadIdx.x == 0 && blockIdx.x == 0) {
    int run = 0;
    for (int i = 0; i < nChunks; ++i) {
      int v = blockSums[i];
      blockSums[i] = run;
      run += v;
    }
  }
}

__global__ __launch_bounds__(256) void scan_chunk_kernel(
    const int* __restrict__ counts, const int* __restrict__ blockOffs,
    int* __restrict__ rowStart, int* __restrict__ cursor, int nNodes) {
  __shared__ int sSum[256];
  int t = threadIdx.x;
  int base = blockIdx.x * CHUNK + t * 4;
  int c0 = 0, c1 = 0, c2 = 0, c3 = 0;
  if (base + 0 < nNodes) c0 = counts[base + 0];
  if (base + 1 < nNodes) c1 = counts[base + 1];
  if (base + 2 < nNodes) c2 = counts[base + 2];
  if (base + 3 < nNodes) c3 = counts[base + 3];
  int local = c0 + c1 + c2 + c3;
  sSum[t] = local;
  __syncthreads();
  for (int off = 1; off < 256; off <<= 1) {
    int v = (t >= off) ? sSum[t - off] : 0;
    __syncthreads();
    sSum[t] += v;
    __syncthreads();
  }
  int excl = blockOffs[blockIdx.x] + sSum[t] - local;
  int p0 = excl, p1 = p0 + c0, p2 = p1 + c1, p3 = p2 + c2;
  if (base + 0 < nNodes) { rowStart[base + 0] = p0; cursor[base + 0] = p0;
                           if (base + 0 == nNodes - 1) rowStart[nNodes] = p1; }
  if (base + 1 < nNodes) { rowStart[base + 1] = p1; cursor[base + 1] = p1;
                           if (base + 1 == nNodes - 1) rowStart[nNodes] = p2; }
  if (base + 2 < nNodes) { rowStart[base + 2] = p2; cursor[base + 2] = p2;
                           if (base + 2 == nNodes - 1) rowStart[nNodes] = p3; }
  if (base + 3 < nNodes) { rowStart[base + 3] = p3; cursor[base + 3] = p3;
                           if (base + 3 == nNodes - 1) rowStart[nNodes] = p3 + c3; }
}

__global__ __launch_bounds__(256) void fill_csr_kernel(
    const int* __restrict__ src, const int* __restrict__ dst,
    int* __restrict__ cursor, int* __restrict__ csrSrc, int nEdges) {
  int e = blockIdx.x * 256 + threadIdx.x;
  if (e >= nEdges) return;
  int pos = atomicAdd(&cursor[dst[e]], 1);
  csrSrc[pos] = src[e];
}

// ================= prep: fp32 -> bf16 =================
__global__ __launch_bounds__(256) void convert_feat_kernel(
    const float* __restrict__ f, unsigned short* __restrict__ o, int nElems) {
  int i = (blockIdx.x * 256 + threadIdx.x) * 4;
  if (i + 3 < nElems) {
    float4 v = *((const float4*)(f + i));
    unsigned a = (unsigned)f2bf(v.x) | ((unsigned)f2bf(v.y) << 16);
    unsigned b = (unsigned)f2bf(v.z) | ((unsigned)f2bf(v.w) << 16);
    *((uint2*)(o + i)) = make_uint2(a, b);
  } else {
    for (int j = i; j < nElems; ++j) o[j] = f2bf(f[j]);
  }
}

// Wt[l][n][k] bf16, k<128 from Wl[k][n], k>=128 from Wr[k-128][n]
__global__ __launch_bounds__(256) void pack_weights_kernel(
    const float* __restrict__ Wl0, const float* __restrict__ Wr0,
    const float* __restrict__ Wl1, const float* __restrict__ Wr1,
    const float* __restrict__ Wl2, const float* __restrict__ Wr2,
    unsigned short* __restrict__ Wt) {
  int t = blockIdx.x * 256 + threadIdx.x;
  if (t >= 3 * 128 * 256) return;
  int l = t >> 15;
  int rem = t & 32767;
  int n = rem >> 8;
  int k = rem & 255;
  const float* Wl = (l == 0) ? Wl0 : (l == 1) ? Wl1 : Wl2;
  const float* Wr = (l == 0) ? Wr0 : (l == 1) ? Wr1 : Wr2;
  float v = (k < 128) ? Wl[k * D + n] : Wr[(k - 128) * D + n];
  Wt[t] = f2bf(v);
}

// ================= gather segment-max on bf16 rows =================
// one wave per node; lane handles one bfloat162 (2 channels)
__global__ __launch_bounds__(256) void gather_max_bf16_kernel(
    const unsigned* __restrict__ x2, const int* __restrict__ rowStart,
    const int* __restrict__ csrSrc, unsigned* __restrict__ agg2, int nNodes) {
  int n = blockIdx.x * 4 + (threadIdx.x >> 6);
  if (n >= nNodes) return;
  int lane = threadIdx.x & 63;
  int e0 = rowStart[n], e1 = rowStart[n + 1];
  float mx = -INFINITY, my = -INFINITY;
  int e = e0;
  for (; e + 1 < e1; e += 2) {
    unsigned u0 = x2[(size_t)csrSrc[e] * 64 + lane];
    unsigned u1 = x2[(size_t)csrSrc[e + 1] * 64 + lane];
    mx = fmaxf(mx, fmaxf(__uint_as_float(u0 << 16), __uint_as_float(u1 << 16)));
    my = fmaxf(my, fmaxf(__uint_as_float(u0 & 0xFFFF0000u),
                         __uint_as_float(u1 & 0xFFFF0000u)));
  }
  if (e < e1) {
    unsigned u0 = x2[(size_t)csrSrc[e] * 64 + lane];
    mx = fmaxf(mx, __uint_as_float(u0 << 16));
    my = fmaxf(my, __uint_as_float(u0 & 0xFFFF0000u));
  }
  unsigned r = 0u;  // isolated node -> two +0.0 bf16
  if (e0 != e1)
    r = (__float_as_uint(mx) >> 16) | (__float_as_uint(my) & 0xFFFF0000u);
  agg2[(size_t)n * 64 + lane] = r;
}

// ================= fused MFMA layer =================
// out = [agg|x](bf16) @ Wt^T + b ; mode<2: ELU+dropout -> bf16 in-place x;
// mode 2: fp32 to outF. Block: 4 waves, 32 rows x 128 cols; 16x16x32 bf16 MFMA.
#define PA 280   // sA pitch (bf16 elems): 140 dw = 12 mod 32 -> 2-way (free)
#define PB 152   // sB pitch: 76 dw = 12 mod 32

__global__ __launch_bounds__(256) void fused_mfma_kernel(
    const unsigned short* __restrict__ aggbf, unsigned short* __restrict__ xbf,
    const unsigned short* __restrict__ Wt, const float* __restrict__ bias,
    float* __restrict__ outF, int nRows, int mode, unsigned kk0, unsigned kk1) {
  __shared__ unsigned short sA[32 * PA];   // 17.9 KB
  __shared__ unsigned short sB[128 * PB];  // 38.9 KB

  const int tid = threadIdx.x;
  const int row0 = blockIdx.x * 32;
  const int wv = tid >> 6, lane = tid & 63;
  const int quad = lane >> 4, m16 = lane & 15;
  const int nbase = wv * 32;

  // ---- stage A: 32 rows x [agg(0..127) | x(128..255)] ----
#pragma unroll
  for (int i = 0; i < 4; ++i) {
    int idx = i * 256 + tid;   // 0..1023 ; 32 segs of 16B per row
    int r = idx >> 5;
    int seg = idx & 31;
    uint4 v = make_uint4(0, 0, 0, 0);
    if (row0 + r < nRows) {
      if (seg < 16) v = ((const uint4*)(aggbf + (size_t)(row0 + r) * D))[seg];
      else          v = ((const uint4*)(xbf  + (size_t)(row0 + r) * D))[seg - 16];
    }
    *((uint4*)(sA + r * PA + seg * 8)) = v;
  }

  floatx4 acc[2][2];
#pragma unroll
  for (int i = 0; i < 2; ++i)
#pragma unroll
    for (int j = 0; j < 2; ++j) acc[i][j] = (floatx4)(0.0f);

  for (int kc = 0; kc < 2; ++kc) {
    __syncthreads();  // covers sA stores (kc=0) and sB reuse (kc=1)
    // stage B chunk: 128 n x 128 k
#pragma unroll
    for (int i = 0; i < 8; ++i) {
      int n = (tid >> 4) + i * 16;
      int seg = tid & 15;
      uint4 v = *((const uint4*)(Wt + (size_t)n * 256 + kc * 128 + seg * 8));
      *((uint4*)(sB + n * PB + seg * 8)) = v;
    }
    __syncthreads();

#pragma unroll
    for (int ks = 0; ks < 4; ++ks) {
      int kA = kc * 128 + ks * 32 + quad * 8;
      int kB = ks * 32 + quad * 8;
      short8 a0 = *((const short8*)(sA + (m16)*PA + kA));
      short8 a1 = *((const short8*)(sA + (m16 + 16) * PA + kA));
      short8 b0 = *((const short8*)(sB + (nbase + m16) * PB + kB));
      short8 b1 = *((const short8*)(sB + (nbase + 16 + m16) * PB + kB));
      acc[0][0] = __builtin_amdgcn_mfma_f32_16x16x32_bf16(a0, b0, acc[0][0], 0, 0, 0);
      acc[0][1] = __builtin_amdgcn_mfma_f32_16x16x32_bf16(a0, b1, acc[0][1], 0, 0, 0);
      acc[1][0] = __builtin_amdgcn_mfma_f32_16x16x32_bf16(a1, b0, acc[1][0], 0, 0, 0);
      acc[1][1] = __builtin_amdgcn_mfma_f32_16x16x32_bf16(a1, b1, acc[1][1], 0, 0, 0);
    }
  }

  // ---- epilogue: C layout col=lane&15, row=quad*4+reg ----
#pragma unroll
  for (int j = 0; j < 2; ++j) {
    int col = nbase + j * 16 + m16;
    float bc = bias[col];
#pragma unroll
    for (int i = 0; i < 2; ++i) {
#pragma unroll
      for (int reg = 0; reg < 4; ++reg) {
        int r = row0 + i * 16 + quad * 4 + reg;
        if (r >= nRows) continue;
        float v = acc[i][j][reg] + bc;
        if (mode < 2) {
          v = (v > 0.0f) ? v : expm1f(v);  // ELU alpha=1
          unsigned jj = (unsigned)r * D + col;
          unsigned y0, y1;
          threefry2x32(kk0, kk1, 0u, jj, y0, y1);
          float u = __uint_as_float((((y0 ^ y1) >> 9)) | 0x3F800000u) - 1.0f;
          v = (u < 0.8f) ? v * 1.25f : 0.0f;
          xbf[(size_t)r * D + col] = f2bf(v);
        } else {
          outF[(size_t)r * D + col] = v;
        }
      }
    }
  }
}

extern "C" void kernel_launch(void* const* d_in, const int* in_sizes, int n_in,
                              void* d_out, int out_size, void* d_ws, size_t ws_size,
                              hipStream_t stream) {
  const float* feat = (const float*)d_in[0];
  const int* ei = (const int*)d_in[1];
  const float* Wl0 = (const float*)d_in[2];
  const float* Wr0 = (const float*)d_in[3];
  const float* b0 = (const float*)d_in[4];
  const float* Wl1 = (const float*)d_in[5];
  const float* Wr1 = (const float*)d_in[6];
  const float* b1 = (const float*)d_in[7];
  const float* Wl2 = (const float*)d_in[8];
  const float* Wr2 = (const float*)d_in[9];
  const float* b2 = (const float*)d_in[10];

  const int N = in_sizes[0] / D;   // 100000
  const int E = in_sizes[1] / 2;   // 1600000
  const int* src = ei;
  const int* dst = ei + E;

  // ---- workspace ----
  const size_t bfBytes = (size_t)N * D * 2;   // 25.6 MB
  char* wsp = (char*)d_ws;
  size_t off = 0;
  unsigned short* xbf   = (unsigned short*)(wsp + off); off += bfBytes;
  unsigned short* aggbf = (unsigned short*)(wsp + off); off += bfBytes;
  unsigned short* Wt    = (unsigned short*)(wsp + off); off += ((size_t)3 * 128 * 256 * 2 + 511) & ~511ull;
  int* rowStart  = (int*)(wsp + off); off += ((size_t)(N + 1) * 4 + 511) & ~511ull;
  int* cursor    = (int*)(wsp + off); off += ((size_t)N * 4 + 511) & ~511ull;
  int* blockSums = (int*)(wsp + off); off += 4096;
  int* csrSrc    = (int*)(wsp + off); off += (size_t)E * 4;

  const int nChunks = (N + CHUNK - 1) / CHUNK;

  // ---- JAX partitionable threefry keys on host ----
  unsigned k1a, k1b, k2a, k2b;
  threefry2x32(0u, 42u, 0u, 0u, k1a, k1b);
  threefry2x32(0u, 42u, 0u, 1u, k2a, k2b);

  // ---- CSR build ----
  hipMemsetAsync(cursor, 0, (size_t)N * 4, stream);
  hist_kernel<<<(E + 255) / 256, 256, 0, stream>>>(dst, cursor, E);
  reduce_chunk_kernel<<<nChunks, 256, 0, stream>>>(cursor, blockSums, N);
  scan_block_sums_kernel<<<1, 64, 0, stream>>>(blockSums, nChunks);
  scan_chunk_kernel<<<nChunks, 256, 0, stream>>>(cursor, blockSums, rowStart, cursor, N);
  fill_csr_kernel<<<(E + 255) / 256, 256, 0, stream>>>(src, dst, cursor, csrSrc, E);

  // ---- prep bf16 ----
  convert_feat_kernel<<<(N * D / 4 + 255) / 256, 256, 0, stream>>>(feat, xbf, N * D);
  pack_weights_kernel<<<(3 * 128 * 256 + 255) / 256, 256, 0, stream>>>(
      Wl0, Wr0, Wl1, Wr1, Wl2, Wr2, Wt);

  dim3 blk(256);
  dim3 grdMax((N + 3) / 4);
  dim3 grdGemm((N + 31) / 32);
  float* outF = (float*)d_out;

  // ---- layer 0 ----
  gather_max_bf16_kernel<<<grdMax, blk, 0, stream>>>((const unsigned*)xbf, rowStart, csrSrc, (unsigned*)aggbf, N);
  fused_mfma_kernel<<<grdGemm, blk, 0, stream>>>(aggbf, xbf, Wt, b0, outF, N, 0, k1a, k1b);

  // ---- layer 1 ----
  gather_max_bf16_kernel<<<grdMax, blk, 0, stream>>>((const unsigned*)xbf, rowStart, csrSrc, (unsigned*)aggbf, N);
  fused_mfma_kernel<<<grdGemm, blk, 0, stream>>>(aggbf, xbf, Wt + 32768, b1, outF, N, 1, k2a, k2b);

  // ---- layer 2 (fp32 out) ----
  gather_max_bf16_kernel<<<grdMax, blk, 0, stream>>>((const unsigned*)xbf, rowStart, csrSrc, (unsigned*)aggbf, N);
  fused_mfma_kernel<<<grdGemm, blk, 0, stream>>>(aggbf, xbf, Wt + 65536, b2, outF, N, 2, 0u, 0u);
}

// Round 5
// 731.495 us; speedup vs baseline: 10.6984x; 1.0622x over previous
//
#include <hip/hip_runtime.h>
#include <math.h>

#define D 128
#define CHUNK 1024

typedef __attribute__((ext_vector_type(8))) short short8;
typedef __attribute__((ext_vector_type(4))) float floatx4;

// ---------------- threefry2x32 (JAX-compatible, 20 rounds) ----------------
__host__ __device__ __forceinline__ unsigned rotl32(unsigned v, int r) {
  return (v << r) | (v >> (32 - r));
}

__host__ __device__ __forceinline__ void threefry2x32(unsigned k0, unsigned k1,
                                                      unsigned x0, unsigned x1,
                                                      unsigned &o0, unsigned &o1) {
  unsigned ks2 = k0 ^ k1 ^ 0x1BD11BDAu;
  unsigned v0 = x0 + k0;
  unsigned v1 = x1 + k1;
  v0 += v1; v1 = rotl32(v1, 13); v1 ^= v0;
  v0 += v1; v1 = rotl32(v1, 15); v1 ^= v0;
  v0 += v1; v1 = rotl32(v1, 26); v1 ^= v0;
  v0 += v1; v1 = rotl32(v1, 6);  v1 ^= v0;
  v0 += k1; v1 += ks2 + 1u;
  v0 += v1; v1 = rotl32(v1, 17); v1 ^= v0;
  v0 += v1; v1 = rotl32(v1, 29); v1 ^= v0;
  v0 += v1; v1 = rotl32(v1, 16); v1 ^= v0;
  v0 += v1; v1 = rotl32(v1, 24); v1 ^= v0;
  v0 += ks2; v1 += k0 + 2u;
  v0 += v1; v1 = rotl32(v1, 13); v1 ^= v0;
  v0 += v1; v1 = rotl32(v1, 15); v1 ^= v0;
  v0 += v1; v1 = rotl32(v1, 26); v1 ^= v0;
  v0 += v1; v1 = rotl32(v1, 6);  v1 ^= v0;
  v0 += k0; v1 += k1 + 3u;
  v0 += v1; v1 = rotl32(v1, 17); v1 ^= v0;
  v0 += v1; v1 = rotl32(v1, 29); v1 ^= v0;
  v0 += v1; v1 = rotl32(v1, 16); v1 ^= v0;
  v0 += v1; v1 = rotl32(v1, 24); v1 ^= v0;
  v0 += k1; v1 += ks2 + 4u;
  v0 += v1; v1 = rotl32(v1, 13); v1 ^= v0;
  v0 += v1; v1 = rotl32(v1, 15); v1 ^= v0;
  v0 += v1; v1 = rotl32(v1, 26); v1 ^= v0;
  v0 += v1; v1 = rotl32(v1, 6);  v1 ^= v0;
  v0 += ks2; v1 += k0 + 5u;
  o0 = v0; o1 = v1;
}

// float -> bf16 (round to nearest even)
__device__ __forceinline__ unsigned short f2bf(float f) {
  unsigned u = __float_as_uint(f);
  unsigned r = u + 0x7FFFu + ((u >> 16) & 1u);
  return (unsigned short)(r >> 16);
}

// ================= CSR build =================
__global__ __launch_bounds__(256) void hist_kernel(
    const int* __restrict__ dst, int* __restrict__ counts, int nEdges) {
  int e = blockIdx.x * 256 + threadIdx.x;
  if (e < nEdges) atomicAdd(&counts[dst[e]], 1);
}

__global__ __launch_bounds__(256) void reduce_chunk_kernel(
    const int* __restrict__ counts, int* __restrict__ blockSums, int nNodes) {
  __shared__ int s[256];
  int t = threadIdx.x;
  int base = blockIdx.x * CHUNK + t * 4;
  int sum = 0;
#pragma unroll
  for (int i = 0; i < 4; ++i)
    if (base + i < nNodes) sum += counts[base + i];
  s[t] = sum;
  __syncthreads();
  for (int off = 128; off > 0; off >>= 1) {
    if (t < off) s[t] += s[t + off];
    __syncthreads();
  }
  if (t == 0) blockSums[blockIdx.x] = s[0];
}

// exclusive-scan blockSums in place (+ total at [n]); also copy to bucketCursor
__global__ void scan_block_sums_kernel(int* blockSums, int* bucketCursor, int nChunks) {
  if (threadIdx.x == 0 && blockIdx.x == 0) {
    int run = 0;
    for (int i = 0; i < nChunks; ++i) {
      int v = blockSums[i];
      blockSums[i] = run;
      bucketCursor[i] = run;
      run += v;
    }
    blockSums[nChunks] = run;
  }
}

__global__ __launch_bounds__(256) void scan_chunk_kernel(
    const int* __restrict__ counts, const int* __restrict__ blockOffs,
    int* __restrict__ rowStart, int* __restrict__ cursor, int nNodes) {
  __shared__ int sSum[256];
  int t = threadIdx.x;
  int base = blockIdx.x * CHUNK + t * 4;
  int c0 = 0, c1 = 0, c2 = 0, c3 = 0;
  if (base + 0 < nNodes) c0 = counts[base + 0];
  if (base + 1 < nNodes) c1 = counts[base + 1];
  if (base + 2 < nNodes) c2 = counts[base + 2];
  if (base + 3 < nNodes) c3 = counts[base + 3];
  int local = c0 + c1 + c2 + c3;
  sSum[t] = local;
  __syncthreads();
  for (int off = 1; off < 256; off <<= 1) {
    int v = (t >= off) ? sSum[t - off] : 0;
    __syncthreads();
    sSum[t] += v;
    __syncthreads();
  }
  int excl = blockOffs[blockIdx.x] + sSum[t] - local;
  int p0 = excl, p1 = p0 + c0, p2 = p1 + c1, p3 = p2 + c2;
  if (base + 0 < nNodes) { rowStart[base + 0] = p0; cursor[base + 0] = p0;
                           if (base + 0 == nNodes - 1) rowStart[nNodes] = p1; }
  if (base + 1 < nNodes) { rowStart[base + 1] = p1; cursor[base + 1] = p1;
                           if (base + 1 == nNodes - 1) rowStart[nNodes] = p2; }
  if (base + 2 < nNodes) { rowStart[base + 2] = p2; cursor[base + 2] = p2;
                           if (base + 2 == nNodes - 1) rowStart[nNodes] = p3; }
  if (base + 3 < nNodes) { rowStart[base + 3] = p3; cursor[base + 3] = p3;
                           if (base + 3 == nNodes - 1) rowStart[nNodes] = p3 + c3; }
}

// ---- two-level bucketed edge partition (kills write-allocate waste) ----
// Each block handles 2048 edges: LDS histogram over buckets (dst>>10), one
// global atomicAdd per touched bucket to reserve a range, then dense appends.
__global__ __launch_bounds__(256) void bucket_scatter_kernel(
    const int* __restrict__ src, const int* __restrict__ dst,
    int* __restrict__ bucketCursor, uint2* __restrict__ pairs,
    int nEdges, int nBuck) {
  __shared__ int lcount[128];
  __shared__ int lbase[128];
  __shared__ int loff[128];
  int t = threadIdx.x;
  if (t < 128) { lcount[t] = 0; loff[t] = 0; }
  __syncthreads();
  int e0 = blockIdx.x * 2048;
  for (int i = t; i < 2048; i += 256) {
    int e = e0 + i;
    if (e < nEdges) atomicAdd(&lcount[dst[e] >> 10], 1);
  }
  __syncthreads();
  if (t < nBuck) {
    int c = lcount[t];
    if (c > 0) lbase[t] = atomicAdd(&bucketCursor[t], c);
  }
  __syncthreads();
  for (int i = t; i < 2048; i += 256) {
    int e = e0 + i;
    if (e < nEdges) {
      int d = dst[e];
      int b = d >> 10;
      int lp = atomicAdd(&loff[b], 1);
      pairs[lbase[b] + lp] = make_uint2((unsigned)src[e], (unsigned)d);
    }
  }
}

// one bucket handled by 4 blocks; csrSrc writes land in the bucket's ~64KB slice
__global__ __launch_bounds__(256) void local_fill_kernel(
    const uint2* __restrict__ pairs, const int* __restrict__ bucketStart,
    int* __restrict__ cursor, int* __restrict__ csrSrc) {
  int b = blockIdx.x >> 2;
  int q = blockIdx.x & 3;
  int s = bucketStart[b];
  int e = bucketStart[b + 1];
  for (int i = s + q * 256 + threadIdx.x; i < e; i += 1024) {
    uint2 p = pairs[i];
    int pos = atomicAdd(&cursor[p.y], 1);
    csrSrc[pos] = (int)p.x;
  }
}

// ================= prep: fp32 -> bf16 =================
__global__ __launch_bounds__(256) void convert_feat_kernel(
    const float* __restrict__ f, unsigned short* __restrict__ o, int nElems) {
  int i = (blockIdx.x * 256 + threadIdx.x) * 4;
  if (i + 3 < nElems) {
    float4 v = *((const float4*)(f + i));
    unsigned a = (unsigned)f2bf(v.x) | ((unsigned)f2bf(v.y) << 16);
    unsigned b = (unsigned)f2bf(v.z) | ((unsigned)f2bf(v.w) << 16);
    *((uint2*)(o + i)) = make_uint2(a, b);
  } else {
    for (int j = i; j < nElems; ++j) o[j] = f2bf(f[j]);
  }
}

// Wt[l][n][k] bf16, k<128 from Wl[k][n], k>=128 from Wr[k-128][n]
__global__ __launch_bounds__(256) void pack_weights_kernel(
    const float* __restrict__ Wl0, const float* __restrict__ Wr0,
    const float* __restrict__ Wl1, const float* __restrict__ Wr1,
    const float* __restrict__ Wl2, const float* __restrict__ Wr2,
    unsigned short* __restrict__ Wt) {
  int t = blockIdx.x * 256 + threadIdx.x;
  if (t >= 3 * 128 * 256) return;
  int l = t >> 15;
  int rem = t & 32767;
  int n = rem >> 8;
  int k = rem & 255;
  const float* Wl = (l == 0) ? Wl0 : (l == 1) ? Wl1 : Wl2;
  const float* Wr = (l == 0) ? Wr0 : (l == 1) ? Wr1 : Wr2;
  float v = (k < 128) ? Wl[k * D + n] : Wr[(k - 128) * D + n];
  Wt[t] = f2bf(v);
}

// ================= gather segment-max on bf16 rows =================
__global__ __launch_bounds__(256) void gather_max_bf16_kernel(
    const unsigned* __restrict__ x2, const int* __restrict__ rowStart,
    const int* __restrict__ csrSrc, unsigned* __restrict__ agg2, int nNodes) {
  int n = blockIdx.x * 4 + (threadIdx.x >> 6);
  if (n >= nNodes) return;
  int lane = threadIdx.x & 63;
  int e0 = rowStart[n], e1 = rowStart[n + 1];
  float mx = -INFINITY, my = -INFINITY;
  int e = e0;
  for (; e + 1 < e1; e += 2) {
    unsigned u0 = x2[(size_t)csrSrc[e] * 64 + lane];
    unsigned u1 = x2[(size_t)csrSrc[e + 1] * 64 + lane];
    mx = fmaxf(mx, fmaxf(__uint_as_float(u0 << 16), __uint_as_float(u1 << 16)));
    my = fmaxf(my, fmaxf(__uint_as_float(u0 & 0xFFFF0000u),
                         __uint_as_float(u1 & 0xFFFF0000u)));
  }
  if (e < e1) {
    unsigned u0 = x2[(size_t)csrSrc[e] * 64 + lane];
    mx = fmaxf(mx, __uint_as_float(u0 << 16));
    my = fmaxf(my, __uint_as_float(u0 & 0xFFFF0000u));
  }
  unsigned r = 0u;  // isolated node -> two +0.0 bf16
  if (e0 != e1)
    r = (__float_as_uint(mx) >> 16) | (__float_as_uint(my) & 0xFFFF0000u);
  agg2[(size_t)n * 64 + lane] = r;
}

// ================= fused MFMA layer (register-resident B) =================
// out = [agg|x](bf16) @ Wt^T + b ; mode<2: ELU+dropout -> bf16 in-place x;
// mode 2: fp32 to outF. Block: 4 waves, 32 rows x 128 cols; 16x16x32 bf16 MFMA.
// B fragments (64 VGPRs/lane) loaded straight from L2-hot Wt; barrier-free K-loop.
#define PA 280   // sA pitch (bf16 elems): 140 dw = 12 mod 32 -> balanced banks

__global__ __launch_bounds__(256) void fused_mfma_kernel(
    const unsigned short* __restrict__ aggbf, unsigned short* __restrict__ xbf,
    const unsigned short* __restrict__ Wt, const float* __restrict__ bias,
    float* __restrict__ outF, int nRows, int mode, unsigned kk0, unsigned kk1) {
  __shared__ unsigned short sA[32 * PA];   // 17.5 KB

  const int tid = threadIdx.x;
  const int row0 = blockIdx.x * 32;
  const int wv = tid >> 6, lane = tid & 63;
  const int quad = lane >> 4, m16 = lane & 15;
  const int nbase = wv * 32;

  // ---- stage A: 32 rows x [agg(0..127) | x(128..255)] ----
#pragma unroll
  for (int i = 0; i < 4; ++i) {
    int idx = i * 256 + tid;   // 32 segs of 16B per row
    int r = idx >> 5;
    int seg = idx & 31;
    uint4 v = make_uint4(0, 0, 0, 0);
    if (row0 + r < nRows) {
      if (seg < 16) v = ((const uint4*)(aggbf + (size_t)(row0 + r) * D))[seg];
      else          v = ((const uint4*)(xbf  + (size_t)(row0 + r) * D))[seg - 16];
    }
    *((uint4*)(sA + r * PA + seg * 8)) = v;
  }

  // ---- B fragments into registers: bfr[kc][ks][j] ----
  short8 bfr[2][4][2];
#pragma unroll
  for (int kc = 0; kc < 2; ++kc)
#pragma unroll
    for (int ks = 0; ks < 4; ++ks)
#pragma unroll
      for (int j = 0; j < 2; ++j)
        bfr[kc][ks][j] = *((const short8*)(
            Wt + (size_t)(nbase + j * 16 + m16) * 256 + kc * 128 + ks * 32 + quad * 8));

  floatx4 acc[2][2];
#pragma unroll
  for (int i = 0; i < 2; ++i)
#pragma unroll
    for (int j = 0; j < 2; ++j) acc[i][j] = (floatx4)(0.0f);

  __syncthreads();

#pragma unroll
  for (int kc = 0; kc < 2; ++kc)
#pragma unroll
    for (int ks = 0; ks < 4; ++ks) {
      int kA = kc * 128 + ks * 32 + quad * 8;
      short8 a0 = *((const short8*)(sA + m16 * PA + kA));
      short8 a1 = *((const short8*)(sA + (m16 + 16) * PA + kA));
      acc[0][0] = __builtin_amdgcn_mfma_f32_16x16x32_bf16(a0, bfr[kc][ks][0], acc[0][0], 0, 0, 0);
      acc[0][1] = __builtin_amdgcn_mfma_f32_16x16x32_bf16(a0, bfr[kc][ks][1], acc[0][1], 0, 0, 0);
      acc[1][0] = __builtin_amdgcn_mfma_f32_16x16x32_bf16(a1, bfr[kc][ks][0], acc[1][0], 0, 0, 0);
      acc[1][1] = __builtin_amdgcn_mfma_f32_16x16x32_bf16(a1, bfr[kc][ks][1], acc[1][1], 0, 0, 0);
    }

  // ---- epilogue: C layout col=lane&15, row=quad*4+reg ----
#pragma unroll
  for (int j = 0; j < 2; ++j) {
    int col = nbase + j * 16 + m16;
    float bc = bias[col];
#pragma unroll
    for (int i = 0; i < 2; ++i) {
#pragma unroll
      for (int reg = 0; reg < 4; ++reg) {
        int r = row0 + i * 16 + quad * 4 + reg;
        if (r >= nRows) continue;
        float v = acc[i][j][reg] + bc;
        if (mode < 2) {
          v = (v > 0.0f) ? v : expm1f(v);  // ELU alpha=1
          unsigned jj = (unsigned)r * D + col;
          unsigned y0, y1;
          threefry2x32(kk0, kk1, 0u, jj, y0, y1);
          float u = __uint_as_float((((y0 ^ y1) >> 9)) | 0x3F800000u) - 1.0f;
          v = (u < 0.8f) ? v * 1.25f : 0.0f;
          xbf[(size_t)r * D + col] = f2bf(v);
        } else {
          outF[(size_t)r * D + col] = v;
        }
      }
    }
  }
}

extern "C" void kernel_launch(void* const* d_in, const int* in_sizes, int n_in,
                              void* d_out, int out_size, void* d_ws, size_t ws_size,
                              hipStream_t stream) {
  const float* feat = (const float*)d_in[0];
  const int* ei = (const int*)d_in[1];
  const float* Wl0 = (const float*)d_in[2];
  const float* Wr0 = (const float*)d_in[3];
  const float* b0 = (const float*)d_in[4];
  const float* Wl1 = (const float*)d_in[5];
  const float* Wr1 = (const float*)d_in[6];
  const float* b1 = (const float*)d_in[7];
  const float* Wl2 = (const float*)d_in[8];
  const float* Wr2 = (const float*)d_in[9];
  const float* b2 = (const float*)d_in[10];

  const int N = in_sizes[0] / D;   // 100000
  const int E = in_sizes[1] / 2;   // 1600000
  const int* src = ei;
  const int* dst = ei + E;

  // ---- workspace ----
  const size_t bfBytes = (size_t)N * D * 2;   // 25.6 MB
  char* wsp = (char*)d_ws;
  size_t off = 0;
  unsigned short* xbf   = (unsigned short*)(wsp + off); off += bfBytes;
  unsigned short* aggbf = (unsigned short*)(wsp + off); off += bfBytes;
  unsigned short* Wt    = (unsigned short*)(wsp + off); off += ((size_t)3 * 128 * 256 * 2 + 511) & ~511ull;
  int* rowStart  = (int*)(wsp + off); off += ((size_t)(N + 1) * 4 + 511) & ~511ull;
  int* cursor    = (int*)(wsp + off); off += ((size_t)N * 4 + 511) & ~511ull;
  int* blockSums = (int*)(wsp + off); off += 2048;
  int* bucketCursor = (int*)(wsp + off); off += 2048;
  int* csrSrc    = (int*)(wsp + off); off += (size_t)E * 4;
  uint2* pairs   = (uint2*)(wsp + off); off += (size_t)E * 8;   // 12.8 MB

  const int nChunks = (N + CHUNK - 1) / CHUNK;  // 98

  // ---- JAX partitionable threefry keys on host ----
  unsigned k1a, k1b, k2a, k2b;
  threefry2x32(0u, 42u, 0u, 0u, k1a, k1b);
  threefry2x32(0u, 42u, 0u, 1u, k2a, k2b);

  // ---- CSR build ----
  hipMemsetAsync(cursor, 0, (size_t)N * 4, stream);
  hist_kernel<<<(E + 255) / 256, 256, 0, stream>>>(dst, cursor, E);
  reduce_chunk_kernel<<<nChunks, 256, 0, stream>>>(cursor, blockSums, N);
  scan_block_sums_kernel<<<1, 64, 0, stream>>>(blockSums, bucketCursor, nChunks);
  scan_chunk_kernel<<<nChunks, 256, 0, stream>>>(cursor, blockSums, rowStart, cursor, N);
  bucket_scatter_kernel<<<(E + 2047) / 2048, 256, 0, stream>>>(src, dst, bucketCursor, pairs, E, nChunks);
  local_fill_kernel<<<4 * nChunks, 256, 0, stream>>>(pairs, blockSums, cursor, csrSrc);

  // ---- prep bf16 ----
  convert_feat_kernel<<<(N * D / 4 + 255) / 256, 256, 0, stream>>>(feat, xbf, N * D);
  pack_weights_kernel<<<(3 * 128 * 256 + 255) / 256, 256, 0, stream>>>(
      Wl0, Wr0, Wl1, Wr1, Wl2, Wr2, Wt);

  dim3 blk(256);
  dim3 grdMax((N + 3) / 4);
  dim3 grdGemm((N + 31) / 32);
  float* outF = (float*)d_out;

  // ---- layer 0 ----
  gather_max_bf16_kernel<<<grdMax, blk, 0, stream>>>((const unsigned*)xbf, rowStart, csrSrc, (unsigned*)aggbf, N);
  fused_mfma_kernel<<<grdGemm, blk, 0, stream>>>(aggbf, xbf, Wt, b0, outF, N, 0, k1a, k1b);

  // ---- layer 1 ----
  gather_max_bf16_kernel<<<grdMax, blk, 0, stream>>>((const unsigned*)xbf, rowStart, csrSrc, (unsigned*)aggbf, N);
  fused_mfma_kernel<<<grdGemm, blk, 0, stream>>>(aggbf, xbf, Wt + 32768, b1, outF, N, 1, k2a, k2b);

  // ---- layer 2 (fp32 out) ----
  gather_max_bf16_kernel<<<grdMax, blk, 0, stream>>>((const unsigned*)xbf, rowStart, csrSrc, (unsigned*)aggbf, N);
  fused_mfma_kernel<<<grdGemm, blk, 0, stream>>>(aggbf, xbf, Wt + 65536, b2, outF, N, 2, 0u, 0u);
}

// Round 6
// 664.110 us; speedup vs baseline: 11.7839x; 1.1015x over previous
//
#include <hip/hip_runtime.h>
#include <math.h>

#define D 128
#define CHUNK 1024

typedef __attribute__((ext_vector_type(8))) short short8;
typedef __attribute__((ext_vector_type(4))) float floatx4;

// ---------------- threefry2x32 (JAX-compatible, 20 rounds) ----------------
__host__ __device__ __forceinline__ unsigned rotl32(unsigned v, int r) {
  return (v << r) | (v >> (32 - r));
}

__host__ __device__ __forceinline__ void threefry2x32(unsigned k0, unsigned k1,
                                                      unsigned x0, unsigned x1,
                                                      unsigned &o0, unsigned &o1) {
  unsigned ks2 = k0 ^ k1 ^ 0x1BD11BDAu;
  unsigned v0 = x0 + k0;
  unsigned v1 = x1 + k1;
  v0 += v1; v1 = rotl32(v1, 13); v1 ^= v0;
  v0 += v1; v1 = rotl32(v1, 15); v1 ^= v0;
  v0 += v1; v1 = rotl32(v1, 26); v1 ^= v0;
  v0 += v1; v1 = rotl32(v1, 6);  v1 ^= v0;
  v0 += k1; v1 += ks2 + 1u;
  v0 += v1; v1 = rotl32(v1, 17); v1 ^= v0;
  v0 += v1; v1 = rotl32(v1, 29); v1 ^= v0;
  v0 += v1; v1 = rotl32(v1, 16); v1 ^= v0;
  v0 += v1; v1 = rotl32(v1, 24); v1 ^= v0;
  v0 += ks2; v1 += k0 + 2u;
  v0 += v1; v1 = rotl32(v1, 13); v1 ^= v0;
  v0 += v1; v1 = rotl32(v1, 15); v1 ^= v0;
  v0 += v1; v1 = rotl32(v1, 26); v1 ^= v0;
  v0 += v1; v1 = rotl32(v1, 6);  v1 ^= v0;
  v0 += k0; v1 += k1 + 3u;
  v0 += v1; v1 = rotl32(v1, 17); v1 ^= v0;
  v0 += v1; v1 = rotl32(v1, 29); v1 ^= v0;
  v0 += v1; v1 = rotl32(v1, 16); v1 ^= v0;
  v0 += v1; v1 = rotl32(v1, 24); v1 ^= v0;
  v0 += k1; v1 += ks2 + 4u;
  v0 += v1; v1 = rotl32(v1, 13); v1 ^= v0;
  v0 += v1; v1 = rotl32(v1, 15); v1 ^= v0;
  v0 += v1; v1 = rotl32(v1, 26); v1 ^= v0;
  v0 += v1; v1 = rotl32(v1, 6);  v1 ^= v0;
  v0 += ks2; v1 += k0 + 5u;
  o0 = v0; o1 = v1;
}

// float -> bf16 (round to nearest even)
__device__ __forceinline__ unsigned short f2bf(float f) {
  unsigned u = __float_as_uint(f);
  unsigned r = u + 0x7FFFu + ((u >> 16) & 1u);
  return (unsigned short)(r >> 16);
}

// ================= CSR build =================
__global__ __launch_bounds__(256) void hist_kernel(
    const int* __restrict__ dst, int* __restrict__ counts, int nEdges) {
  int e = blockIdx.x * 256 + threadIdx.x;
  if (e < nEdges) atomicAdd(&counts[dst[e]], 1);
}

__global__ __launch_bounds__(256) void reduce_chunk_kernel(
    const int* __restrict__ counts, int* __restrict__ blockSums, int nNodes) {
  __shared__ int s[256];
  int t = threadIdx.x;
  int base = blockIdx.x * CHUNK + t * 4;
  int sum = 0;
#pragma unroll
  for (int i = 0; i < 4; ++i)
    if (base + i < nNodes) sum += counts[base + i];
  s[t] = sum;
  __syncthreads();
  for (int off = 128; off > 0; off >>= 1) {
    if (t < off) s[t] += s[t + off];
    __syncthreads();
  }
  if (t == 0) blockSums[blockIdx.x] = s[0];
}

// exclusive-scan blockSums in place (+ total at [n]); also copy to bucketCursor
__global__ void scan_block_sums_kernel(int* blockSums, int* bucketCursor, int nChunks) {
  if (threadIdx.x == 0 && blockIdx.x == 0) {
    int run = 0;
    for (int i = 0; i < nChunks; ++i) {
      int v = blockSums[i];
      blockSums[i] = run;
      bucketCursor[i] = run;
      run += v;
    }
    blockSums[nChunks] = run;
  }
}

__global__ __launch_bounds__(256) void scan_chunk_kernel(
    const int* __restrict__ counts, const int* __restrict__ blockOffs,
    int* __restrict__ rowStart, int* __restrict__ cursor, int nNodes) {
  __shared__ int sSum[256];
  int t = threadIdx.x;
  int base = blockIdx.x * CHUNK + t * 4;
  int c0 = 0, c1 = 0, c2 = 0, c3 = 0;
  if (base + 0 < nNodes) c0 = counts[base + 0];
  if (base + 1 < nNodes) c1 = counts[base + 1];
  if (base + 2 < nNodes) c2 = counts[base + 2];
  if (base + 3 < nNodes) c3 = counts[base + 3];
  int local = c0 + c1 + c2 + c3;
  sSum[t] = local;
  __syncthreads();
  for (int off = 1; off < 256; off <<= 1) {
    int v = (t >= off) ? sSum[t - off] : 0;
    __syncthreads();
    sSum[t] += v;
    __syncthreads();
  }
  int excl = blockOffs[blockIdx.x] + sSum[t] - local;
  int p0 = excl, p1 = p0 + c0, p2 = p1 + c1, p3 = p2 + c2;
  if (base + 0 < nNodes) { rowStart[base + 0] = p0; cursor[base + 0] = p0;
                           if (base + 0 == nNodes - 1) rowStart[nNodes] = p1; }
  if (base + 1 < nNodes) { rowStart[base + 1] = p1; cursor[base + 1] = p1;
                           if (base + 1 == nNodes - 1) rowStart[nNodes] = p2; }
  if (base + 2 < nNodes) { rowStart[base + 2] = p2; cursor[base + 2] = p2;
                           if (base + 2 == nNodes - 1) rowStart[nNodes] = p3; }
  if (base + 3 < nNodes) { rowStart[base + 3] = p3; cursor[base + 3] = p3;
                           if (base + 3 == nNodes - 1) rowStart[nNodes] = p3 + c3; }
}

// ---- two-level bucketed edge partition (kills write-allocate waste) ----
__global__ __launch_bounds__(256) void bucket_scatter_kernel(
    const int* __restrict__ src, const int* __restrict__ dst,
    int* __restrict__ bucketCursor, uint2* __restrict__ pairs,
    int nEdges, int nBuck) {
  __shared__ int lcount[128];
  __shared__ int lbase[128];
  __shared__ int loff[128];
  int t = threadIdx.x;
  if (t < 128) { lcount[t] = 0; loff[t] = 0; }
  __syncthreads();
  int e0 = blockIdx.x * 2048;
  for (int i = t; i < 2048; i += 256) {
    int e = e0 + i;
    if (e < nEdges) atomicAdd(&lcount[dst[e] >> 10], 1);
  }
  __syncthreads();
  if (t < nBuck) {
    int c = lcount[t];
    if (c > 0) lbase[t] = atomicAdd(&bucketCursor[t], c);
  }
  __syncthreads();
  for (int i = t; i < 2048; i += 256) {
    int e = e0 + i;
    if (e < nEdges) {
      int d = dst[e];
      int b = d >> 10;
      int lp = atomicAdd(&loff[b], 1);
      pairs[lbase[b] + lp] = make_uint2((unsigned)src[e], (unsigned)d);
    }
  }
}

// one bucket handled by 4 blocks; csrSrc writes land in the bucket's ~64KB slice
__global__ __launch_bounds__(256) void local_fill_kernel(
    const uint2* __restrict__ pairs, const int* __restrict__ bucketStart,
    int* __restrict__ cursor, int* __restrict__ csrSrc) {
  int b = blockIdx.x >> 2;
  int q = blockIdx.x & 3;
  int s = bucketStart[b];
  int e = bucketStart[b + 1];
  for (int i = s + q * 256 + threadIdx.x; i < e; i += 1024) {
    uint2 p = pairs[i];
    int pos = atomicAdd(&cursor[p.y], 1);
    csrSrc[pos] = (int)p.x;
  }
}

// ================= prep: fp32 -> bf16 =================
__global__ __launch_bounds__(256) void convert_feat_kernel(
    const float* __restrict__ f, unsigned short* __restrict__ o, int nElems) {
  int i = (blockIdx.x * 256 + threadIdx.x) * 4;
  if (i + 3 < nElems) {
    float4 v = *((const float4*)(f + i));
    unsigned a = (unsigned)f2bf(v.x) | ((unsigned)f2bf(v.y) << 16);
    unsigned b = (unsigned)f2bf(v.z) | ((unsigned)f2bf(v.w) << 16);
    *((uint2*)(o + i)) = make_uint2(a, b);
  } else {
    for (int j = i; j < nElems; ++j) o[j] = f2bf(f[j]);
  }
}

// Wt[l][n][k] bf16, k<128 from Wl[k][n], k>=128 from Wr[k-128][n]
__global__ __launch_bounds__(256) void pack_weights_kernel(
    const float* __restrict__ Wl0, const float* __restrict__ Wr0,
    const float* __restrict__ Wl1, const float* __restrict__ Wr1,
    const float* __restrict__ Wl2, const float* __restrict__ Wr2,
    unsigned short* __restrict__ Wt) {
  int t = blockIdx.x * 256 + threadIdx.x;
  if (t >= 3 * 128 * 256) return;
  int l = t >> 15;
  int rem = t & 32767;
  int n = rem >> 8;
  int k = rem & 255;
  const float* Wl = (l == 0) ? Wl0 : (l == 1) ? Wl1 : Wl2;
  const float* Wr = (l == 0) ? Wr0 : (l == 1) ? Wr1 : Wr2;
  float v = (k < 128) ? Wl[k * D + n] : Wr[(k - 128) * D + n];
  Wt[t] = f2bf(v);
}

// ================= gather segment-max on bf16 rows =================
// One wave per node. 8 B/lane: 32 lanes cover a 256 B row; the two 32-lane
// halves take different edges -> 4 edges per iter from 2 loads/lane.
__global__ __launch_bounds__(256) void gather_max_bf16_kernel(
    const uint2* __restrict__ x4, const int* __restrict__ rowStart,
    const int* __restrict__ csrSrc, uint2* __restrict__ agg4, int nNodes) {
  int n = blockIdx.x * 4 + (threadIdx.x >> 6);
  if (n >= nNodes) return;
  int lane = threadIdx.x & 63;
  int h = lane >> 5;        // which edge of a pair this half-wave takes
  int l32 = lane & 31;      // 8-byte segment within the row
  int e0 = rowStart[n], e1 = rowStart[n + 1];
  float m0 = -INFINITY, m1 = -INFINITY, m2 = -INFINITY, m3 = -INFINITY;
  int e = e0;
  for (; e + 3 < e1; e += 4) {
    int sa = csrSrc[e + h];
    int sb = csrSrc[e + 2 + h];
    uint2 va = x4[(size_t)sa * 32 + l32];
    uint2 vb = x4[(size_t)sb * 32 + l32];
    m0 = fmaxf(m0, fmaxf(__uint_as_float(va.x << 16), __uint_as_float(vb.x << 16)));
    m1 = fmaxf(m1, fmaxf(__uint_as_float(va.x & 0xFFFF0000u),
                         __uint_as_float(vb.x & 0xFFFF0000u)));
    m2 = fmaxf(m2, fmaxf(__uint_as_float(va.y << 16), __uint_as_float(vb.y << 16)));
    m3 = fmaxf(m3, fmaxf(__uint_as_float(va.y & 0xFFFF0000u),
                         __uint_as_float(vb.y & 0xFFFF0000u)));
  }
  if (e + 1 < e1) {  // 2-edge tail: half h takes edge e+h
    int sa = csrSrc[e + h];
    uint2 va = x4[(size_t)sa * 32 + l32];
    m0 = fmaxf(m0, __uint_as_float(va.x << 16));
    m1 = fmaxf(m1, __uint_as_float(va.x & 0xFFFF0000u));
    m2 = fmaxf(m2, __uint_as_float(va.y << 16));
    m3 = fmaxf(m3, __uint_as_float(va.y & 0xFFFF0000u));
    e += 2;
  }
  if (e < e1) {      // single leftover edge: both halves read it (same line)
    int sa = csrSrc[e];
    uint2 va = x4[(size_t)sa * 32 + l32];
    m0 = fmaxf(m0, __uint_as_float(va.x << 16));
    m1 = fmaxf(m1, __uint_as_float(va.x & 0xFFFF0000u));
    m2 = fmaxf(m2, __uint_as_float(va.y << 16));
    m3 = fmaxf(m3, __uint_as_float(va.y & 0xFFFF0000u));
  }
  // combine the two halves
  m0 = fmaxf(m0, __shfl_xor(m0, 32, 64));
  m1 = fmaxf(m1, __shfl_xor(m1, 32, 64));
  m2 = fmaxf(m2, __shfl_xor(m2, 32, 64));
  m3 = fmaxf(m3, __shfl_xor(m3, 32, 64));
  uint2 r = make_uint2(0u, 0u);  // isolated node -> +0.0
  if (e0 != e1) {
    r.x = (__float_as_uint(m0) >> 16) | (__float_as_uint(m1) & 0xFFFF0000u);
    r.y = (__float_as_uint(m2) >> 16) | (__float_as_uint(m3) & 0xFFFF0000u);
  }
  if (h == 0) agg4[(size_t)n * 32 + l32] = r;
}

// ================= fused MFMA layer (register-resident B) =================
#define PA 280   // sA pitch (bf16 elems): 140 dw = 12 mod 32 -> balanced banks

__global__ __launch_bounds__(256) void fused_mfma_kernel(
    const unsigned short* __restrict__ aggbf, unsigned short* __restrict__ xbf,
    const unsigned short* __restrict__ Wt, const float* __restrict__ bias,
    float* __restrict__ outF, int nRows, int mode, unsigned kk0, unsigned kk1) {
  __shared__ unsigned short sA[32 * PA];   // 17.5 KB

  const int tid = threadIdx.x;
  const int row0 = blockIdx.x * 32;
  const int wv = tid >> 6, lane = tid & 63;
  const int quad = lane >> 4, m16 = lane & 15;
  const int nbase = wv * 32;

  // ---- stage A: 32 rows x [agg(0..127) | x(128..255)] ----
#pragma unroll
  for (int i = 0; i < 4; ++i) {
    int idx = i * 256 + tid;   // 32 segs of 16B per row
    int r = idx >> 5;
    int seg = idx & 31;
    uint4 v = make_uint4(0, 0, 0, 0);
    if (row0 + r < nRows) {
      if (seg < 16) v = ((const uint4*)(aggbf + (size_t)(row0 + r) * D))[seg];
      else          v = ((const uint4*)(xbf  + (size_t)(row0 + r) * D))[seg - 16];
    }
    *((uint4*)(sA + r * PA + seg * 8)) = v;
  }

  // ---- B fragments into registers: bfr[kc][ks][j] ----
  short8 bfr[2][4][2];
#pragma unroll
  for (int kc = 0; kc < 2; ++kc)
#pragma unroll
    for (int ks = 0; ks < 4; ++ks)
#pragma unroll
      for (int j = 0; j < 2; ++j)
        bfr[kc][ks][j] = *((const short8*)(
            Wt + (size_t)(nbase + j * 16 + m16) * 256 + kc * 128 + ks * 32 + quad * 8));

  floatx4 acc[2][2];
#pragma unroll
  for (int i = 0; i < 2; ++i)
#pragma unroll
    for (int j = 0; j < 2; ++j) acc[i][j] = (floatx4)(0.0f);

  __syncthreads();

#pragma unroll
  for (int kc = 0; kc < 2; ++kc)
#pragma unroll
    for (int ks = 0; ks < 4; ++ks) {
      int kA = kc * 128 + ks * 32 + quad * 8;
      short8 a0 = *((const short8*)(sA + m16 * PA + kA));
      short8 a1 = *((const short8*)(sA + (m16 + 16) * PA + kA));
      acc[0][0] = __builtin_amdgcn_mfma_f32_16x16x32_bf16(a0, bfr[kc][ks][0], acc[0][0], 0, 0, 0);
      acc[0][1] = __builtin_amdgcn_mfma_f32_16x16x32_bf16(a0, bfr[kc][ks][1], acc[0][1], 0, 0, 0);
      acc[1][0] = __builtin_amdgcn_mfma_f32_16x16x32_bf16(a1, bfr[kc][ks][0], acc[1][0], 0, 0, 0);
      acc[1][1] = __builtin_amdgcn_mfma_f32_16x16x32_bf16(a1, bfr[kc][ks][1], acc[1][1], 0, 0, 0);
    }

  // ---- epilogue: C layout col=lane&15, row=quad*4+reg ----
#pragma unroll
  for (int j = 0; j < 2; ++j) {
    int col = nbase + j * 16 + m16;
    float bc = bias[col];
#pragma unroll
    for (int i = 0; i < 2; ++i) {
#pragma unroll
      for (int reg = 0; reg < 4; ++reg) {
        int r = row0 + i * 16 + quad * 4 + reg;
        if (r >= nRows) continue;
        float v = acc[i][j][reg] + bc;
        if (mode < 2) {
          v = (v > 0.0f) ? v : expm1f(v);  // ELU alpha=1
          unsigned jj = (unsigned)r * D + col;
          unsigned y0, y1;
          threefry2x32(kk0, kk1, 0u, jj, y0, y1);
          float u = __uint_as_float((((y0 ^ y1) >> 9)) | 0x3F800000u) - 1.0f;
          v = (u < 0.8f) ? v * 1.25f : 0.0f;
          xbf[(size_t)r * D + col] = f2bf(v);
        } else {
          outF[(size_t)r * D + col] = v;
        }
      }
    }
  }
}

extern "C" void kernel_launch(void* const* d_in, const int* in_sizes, int n_in,
                              void* d_out, int out_size, void* d_ws, size_t ws_size,
                              hipStream_t stream) {
  const float* feat = (const float*)d_in[0];
  const int* ei = (const int*)d_in[1];
  const float* Wl0 = (const float*)d_in[2];
  const float* Wr0 = (const float*)d_in[3];
  const float* b0 = (const float*)d_in[4];
  const float* Wl1 = (const float*)d_in[5];
  const float* Wr1 = (const float*)d_in[6];
  const float* b1 = (const float*)d_in[7];
  const float* Wl2 = (const float*)d_in[8];
  const float* Wr2 = (const float*)d_in[9];
  const float* b2 = (const float*)d_in[10];

  const int N = in_sizes[0] / D;   // 100000
  const int E = in_sizes[1] / 2;   // 1600000
  const int* src = ei;
  const int* dst = ei + E;

  // ---- workspace ----
  const size_t bfBytes = (size_t)N * D * 2;   // 25.6 MB
  char* wsp = (char*)d_ws;
  size_t off = 0;
  unsigned short* xbf   = (unsigned short*)(wsp + off); off += bfBytes;
  unsigned short* aggbf = (unsigned short*)(wsp + off); off += bfBytes;
  unsigned short* Wt    = (unsigned short*)(wsp + off); off += ((size_t)3 * 128 * 256 * 2 + 511) & ~511ull;
  int* rowStart  = (int*)(wsp + off); off += ((size_t)(N + 1) * 4 + 511) & ~511ull;
  int* cursor    = (int*)(wsp + off); off += ((size_t)N * 4 + 511) & ~511ull;
  int* blockSums = (int*)(wsp + off); off += 2048;
  int* bucketCursor = (int*)(wsp + off); off += 2048;
  int* csrSrc    = (int*)(wsp + off); off += (size_t)E * 4;
  uint2* pairs   = (uint2*)(wsp + off); off += (size_t)E * 8;   // 12.8 MB

  const int nChunks = (N + CHUNK - 1) / CHUNK;  // 98

  // ---- JAX partitionable threefry keys on host ----
  unsigned k1a, k1b, k2a, k2b;
  threefry2x32(0u, 42u, 0u, 0u, k1a, k1b);
  threefry2x32(0u, 42u, 0u, 1u, k2a, k2b);

  // ---- CSR build ----
  hipMemsetAsync(cursor, 0, (size_t)N * 4, stream);
  hist_kernel<<<(E + 255) / 256, 256, 0, stream>>>(dst, cursor, E);
  reduce_chunk_kernel<<<nChunks, 256, 0, stream>>>(cursor, blockSums, N);
  scan_block_sums_kernel<<<1, 64, 0, stream>>>(blockSums, bucketCursor, nChunks);
  scan_chunk_kernel<<<nChunks, 256, 0, stream>>>(cursor, blockSums, rowStart, cursor, N);
  bucket_scatter_kernel<<<(E + 2047) / 2048, 256, 0, stream>>>(src, dst, bucketCursor, pairs, E, nChunks);
  local_fill_kernel<<<4 * nChunks, 256, 0, stream>>>(pairs, blockSums, cursor, csrSrc);

  // ---- prep bf16 ----
  convert_feat_kernel<<<(N * D / 4 + 255) / 256, 256, 0, stream>>>(feat, xbf, N * D);
  pack_weights_kernel<<<(3 * 128 * 256 + 255) / 256, 256, 0, stream>>>(
      Wl0, Wr0, Wl1, Wr1, Wl2, Wr2, Wt);

  dim3 blk(256);
  dim3 grdMax((N + 3) / 4);
  dim3 grdGemm((N + 31) / 32);
  float* outF = (float*)d_out;

  // ---- layer 0 ----
  gather_max_bf16_kernel<<<grdMax, blk, 0, stream>>>((const uint2*)xbf, rowStart, csrSrc, (uint2*)aggbf, N);
  fused_mfma_kernel<<<grdGemm, blk, 0, stream>>>(aggbf, xbf, Wt, b0, outF, N, 0, k1a, k1b);

  // ---- layer 1 ----
  gather_max_bf16_kernel<<<grdMax, blk, 0, stream>>>((const uint2*)xbf, rowStart, csrSrc, (uint2*)aggbf, N);
  fused_mfma_kernel<<<grdGemm, blk, 0, stream>>>(aggbf, xbf, Wt + 32768, b1, outF, N, 1, k2a, k2b);

  // ---- layer 2 (fp32 out) ----
  gather_max_bf16_kernel<<<grdMax, blk, 0, stream>>>((const uint2*)xbf, rowStart, csrSrc, (uint2*)aggbf, N);
  fused_mfma_kernel<<<grdGemm, blk, 0, stream>>>(aggbf, xbf, Wt + 65536, b2, outF, N, 2, 0u, 0u);
}

// Round 7
// 616.057 us; speedup vs baseline: 12.7031x; 1.0780x over previous
//
#include <hip/hip_runtime.h>
#include <math.h>

#define D 128
#define CHUNK 1024
#define BSHIFT 9              // bucket = 512 nodes
#define BCAP 12288            // LDS staging capacity (edges) per bucket

typedef __attribute__((ext_vector_type(8))) short short8;
typedef __attribute__((ext_vector_type(4))) float floatx4;

// ---------------- threefry2x32 (JAX-compatible, 20 rounds) ----------------
__host__ __device__ __forceinline__ unsigned rotl32(unsigned v, int r) {
  return (v << r) | (v >> (32 - r));
}

__host__ __device__ __forceinline__ void threefry2x32(unsigned k0, unsigned k1,
                                                      unsigned x0, unsigned x1,
                                                      unsigned &o0, unsigned &o1) {
  unsigned ks2 = k0 ^ k1 ^ 0x1BD11BDAu;
  unsigned v0 = x0 + k0;
  unsigned v1 = x1 + k1;
  v0 += v1; v1 = rotl32(v1, 13); v1 ^= v0;
  v0 += v1; v1 = rotl32(v1, 15); v1 ^= v0;
  v0 += v1; v1 = rotl32(v1, 26); v1 ^= v0;
  v0 += v1; v1 = rotl32(v1, 6);  v1 ^= v0;
  v0 += k1; v1 += ks2 + 1u;
  v0 += v1; v1 = rotl32(v1, 17); v1 ^= v0;
  v0 += v1; v1 = rotl32(v1, 29); v1 ^= v0;
  v0 += v1; v1 = rotl32(v1, 16); v1 ^= v0;
  v0 += v1; v1 = rotl32(v1, 24); v1 ^= v0;
  v0 += ks2; v1 += k0 + 2u;
  v0 += v1; v1 = rotl32(v1, 13); v1 ^= v0;
  v0 += v1; v1 = rotl32(v1, 15); v1 ^= v0;
  v0 += v1; v1 = rotl32(v1, 26); v1 ^= v0;
  v0 += v1; v1 = rotl32(v1, 6);  v1 ^= v0;
  v0 += k0; v1 += k1 + 3u;
  v0 += v1; v1 = rotl32(v1, 17); v1 ^= v0;
  v0 += v1; v1 = rotl32(v1, 29); v1 ^= v0;
  v0 += v1; v1 = rotl32(v1, 16); v1 ^= v0;
  v0 += v1; v1 = rotl32(v1, 24); v1 ^= v0;
  v0 += k1; v1 += ks2 + 4u;
  v0 += v1; v1 = rotl32(v1, 13); v1 ^= v0;
  v0 += v1; v1 = rotl32(v1, 15); v1 ^= v0;
  v0 += v1; v1 = rotl32(v1, 26); v1 ^= v0;
  v0 += v1; v1 = rotl32(v1, 6);  v1 ^= v0;
  v0 += ks2; v1 += k0 + 5u;
  o0 = v0; o1 = v1;
}

// float -> bf16 (round to nearest even)
__device__ __forceinline__ unsigned short f2bf(float f) {
  unsigned u = __float_as_uint(f);
  unsigned r = u + 0x7FFFu + ((u >> 16) & 1u);
  return (unsigned short)(r >> 16);
}

// ================= CSR build =================
__global__ __launch_bounds__(256) void hist_kernel(
    const int* __restrict__ dst, int* __restrict__ counts, int nEdges) {
  int e = blockIdx.x * 256 + threadIdx.x;
  if (e < nEdges) atomicAdd(&counts[dst[e]], 1);
}

__global__ __launch_bounds__(256) void reduce_chunk_kernel(
    const int* __restrict__ counts, int* __restrict__ blockSums, int nNodes) {
  __shared__ int s[256];
  int t = threadIdx.x;
  int base = blockIdx.x * CHUNK + t * 4;
  int sum = 0;
#pragma unroll
  for (int i = 0; i < 4; ++i)
    if (base + i < nNodes) sum += counts[base + i];
  s[t] = sum;
  __syncthreads();
  for (int off = 128; off > 0; off >>= 1) {
    if (t < off) s[t] += s[t + off];
    __syncthreads();
  }
  if (t == 0) blockSums[blockIdx.x] = s[0];
}

// exclusive-scan blockSums in place (+ total at [n])
__global__ void scan_block_sums_kernel(int* blockSums, int nChunks) {
  if (threadIdx.x == 0 && blockIdx.x == 0) {
    int run = 0;
    for (int i = 0; i < nChunks; ++i) {
      int v = blockSums[i];
      blockSums[i] = run;
      run += v;
    }
    blockSums[nChunks] = run;
  }
}

__global__ __launch_bounds__(256) void scan_chunk_kernel(
    const int* __restrict__ counts, const int* __restrict__ blockOffs,
    int* __restrict__ rowStart, int* __restrict__ cursor, int nNodes) {
  __shared__ int sSum[256];
  int t = threadIdx.x;
  int base = blockIdx.x * CHUNK + t * 4;
  int c0 = 0, c1 = 0, c2 = 0, c3 = 0;
  if (base + 0 < nNodes) c0 = counts[base + 0];
  if (base + 1 < nNodes) c1 = counts[base + 1];
  if (base + 2 < nNodes) c2 = counts[base + 2];
  if (base + 3 < nNodes) c3 = counts[base + 3];
  int local = c0 + c1 + c2 + c3;
  sSum[t] = local;
  __syncthreads();
  for (int off = 1; off < 256; off <<= 1) {
    int v = (t >= off) ? sSum[t - off] : 0;
    __syncthreads();
    sSum[t] += v;
    __syncthreads();
  }
  int excl = blockOffs[blockIdx.x] + sSum[t] - local;
  int p0 = excl, p1 = p0 + c0, p2 = p1 + c1, p3 = p2 + c2;
  if (base + 0 < nNodes) { rowStart[base + 0] = p0; cursor[base + 0] = p0;
                           if (base + 0 == nNodes - 1) rowStart[nNodes] = p1; }
  if (base + 1 < nNodes) { rowStart[base + 1] = p1; cursor[base + 1] = p1;
                           if (base + 1 == nNodes - 1) rowStart[nNodes] = p2; }
  if (base + 2 < nNodes) { rowStart[base + 2] = p2; cursor[base + 2] = p2;
                           if (base + 2 == nNodes - 1) rowStart[nNodes] = p3; }
  if (base + 3 < nNodes) { rowStart[base + 3] = p3; cursor[base + 3] = p3;
                           if (base + 3 == nNodes - 1) rowStart[nNodes] = p3 + c3; }
}

// bucketCursor[b] = rowStart[min(b*512, N)] -> pairs regions == CSR regions
__global__ void init_bucket_cursor_kernel(
    const int* __restrict__ rowStart, int* __restrict__ bucketCursor,
    int nBuck, int nNodes) {
  int b = blockIdx.x * 256 + threadIdx.x;
  if (b <= nBuck) {
    int n = b << BSHIFT;
    if (n > nNodes) n = nNodes;
    bucketCursor[b] = rowStart[n];
  }
}

// ---- two-level bucketed edge partition (kills write-allocate waste) ----
__global__ __launch_bounds__(256) void bucket_scatter_kernel(
    const int* __restrict__ src, const int* __restrict__ dst,
    int* __restrict__ bucketCursor, uint2* __restrict__ pairs,
    int nEdges, int nBuck) {
  __shared__ int lcount[256];
  __shared__ int lbase[256];
  __shared__ int loff[256];
  int t = threadIdx.x;
  lcount[t] = 0; loff[t] = 0;
  __syncthreads();
  int e0 = blockIdx.x * 2048;
  for (int i = t; i < 2048; i += 256) {
    int e = e0 + i;
    if (e < nEdges) atomicAdd(&lcount[dst[e] >> BSHIFT], 1);
  }
  __syncthreads();
  if (t < nBuck) {
    int c = lcount[t];
    if (c > 0) lbase[t] = atomicAdd(&bucketCursor[t], c);
  }
  __syncthreads();
  for (int i = t; i < 2048; i += 256) {
    int e = e0 + i;
    if (e < nEdges) {
      int d = dst[e];
      int b = d >> BSHIFT;
      int lp = atomicAdd(&loff[b], 1);
      pairs[lbase[b] + lp] = make_uint2((unsigned)src[e], (unsigned)d);
    }
  }
}

// One block per bucket: scatter src into LDS staging via LDS atomics, then
// stream out contiguously (single-writer, full-line writes -> no WA waste).
__global__ __launch_bounds__(256) void local_fill_kernel(
    const uint2* __restrict__ pairs, const int* __restrict__ rowStart,
    int* __restrict__ cursor, int* __restrict__ csrSrc, int nNodes) {
  __shared__ int sData[BCAP];           // 48 KB
  __shared__ int lcur[1 << BSHIFT];     // 2 KB
  int b = blockIdx.x;
  int node0 = b << BSHIFT;
  int node1 = node0 + (1 << BSHIFT);
  if (node1 > nNodes) node1 = nNodes;
  int base = rowStart[node0];
  int end = rowStart[node1];
  int cnt = end - base;
  int t = threadIdx.x;
  for (int i = t; i < node1 - node0; i += 256)
    lcur[i] = rowStart[node0 + i] - base;
  __syncthreads();
  if (cnt <= BCAP) {
    for (int i = base + t; i < end; i += 256) {
      uint2 p = pairs[i];
      int lp = atomicAdd(&lcur[p.y - (unsigned)node0], 1);
      sData[lp] = (int)p.x;
    }
    __syncthreads();
    for (int i = t; i < cnt; i += 256)
      csrSrc[base + i] = sData[i];
  } else {
    // deterministic-capacity fallback (never expected for this dataset)
    for (int i = base + t; i < end; i += 256) {
      uint2 p = pairs[i];
      int pos = atomicAdd(&cursor[p.y], 1);
      csrSrc[pos] = (int)p.x;
    }
  }
}

// ================= prep: fp32 -> bf16 =================
__global__ __launch_bounds__(256) void convert_feat_kernel(
    const float* __restrict__ f, unsigned short* __restrict__ o, int nElems) {
  int i = (blockIdx.x * 256 + threadIdx.x) * 4;
  if (i + 3 < nElems) {
    float4 v = *((const float4*)(f + i));
    unsigned a = (unsigned)f2bf(v.x) | ((unsigned)f2bf(v.y) << 16);
    unsigned b = (unsigned)f2bf(v.z) | ((unsigned)f2bf(v.w) << 16);
    *((uint2*)(o + i)) = make_uint2(a, b);
  } else {
    for (int j = i; j < nElems; ++j) o[j] = f2bf(f[j]);
  }
}

// Wt[l][n][k] bf16, k<128 from Wl[k][n], k>=128 from Wr[k-128][n]
__global__ __launch_bounds__(256) void pack_weights_kernel(
    const float* __restrict__ Wl0, const float* __restrict__ Wr0,
    const float* __restrict__ Wl1, const float* __restrict__ Wr1,
    const float* __restrict__ Wl2, const float* __restrict__ Wr2,
    unsigned short* __restrict__ Wt) {
  int t = blockIdx.x * 256 + threadIdx.x;
  if (t >= 3 * 128 * 256) return;
  int l = t >> 15;
  int rem = t & 32767;
  int n = rem >> 8;
  int k = rem & 255;
  const float* Wl = (l == 0) ? Wl0 : (l == 1) ? Wl1 : Wl2;
  const float* Wr = (l == 0) ? Wr0 : (l == 1) ? Wr1 : Wr2;
  float v = (k < 128) ? Wl[k * D + n] : Wr[(k - 128) * D + n];
  Wt[t] = f2bf(v);
}

// ================= gather segment-max on bf16 rows =================
__global__ __launch_bounds__(256) void gather_max_bf16_kernel(
    const uint2* __restrict__ x4, const int* __restrict__ rowStart,
    const int* __restrict__ csrSrc, uint2* __restrict__ agg4, int nNodes) {
  int n = blockIdx.x * 4 + (threadIdx.x >> 6);
  if (n >= nNodes) return;
  int lane = threadIdx.x & 63;
  int h = lane >> 5;
  int l32 = lane & 31;
  int e0 = rowStart[n], e1 = rowStart[n + 1];
  float m0 = -INFINITY, m1 = -INFINITY, m2 = -INFINITY, m3 = -INFINITY;
  int e = e0;
  for (; e + 3 < e1; e += 4) {
    int sa = csrSrc[e + h];
    int sb = csrSrc[e + 2 + h];
    uint2 va = x4[(size_t)sa * 32 + l32];
    uint2 vb = x4[(size_t)sb * 32 + l32];
    m0 = fmaxf(m0, fmaxf(__uint_as_float(va.x << 16), __uint_as_float(vb.x << 16)));
    m1 = fmaxf(m1, fmaxf(__uint_as_float(va.x & 0xFFFF0000u),
                         __uint_as_float(vb.x & 0xFFFF0000u)));
    m2 = fmaxf(m2, fmaxf(__uint_as_float(va.y << 16), __uint_as_float(vb.y << 16)));
    m3 = fmaxf(m3, fmaxf(__uint_as_float(va.y & 0xFFFF0000u),
                         __uint_as_float(vb.y & 0xFFFF0000u)));
  }
  if (e + 1 < e1) {
    int sa = csrSrc[e + h];
    uint2 va = x4[(size_t)sa * 32 + l32];
    m0 = fmaxf(m0, __uint_as_float(va.x << 16));
    m1 = fmaxf(m1, __uint_as_float(va.x & 0xFFFF0000u));
    m2 = fmaxf(m2, __uint_as_float(va.y << 16));
    m3 = fmaxf(m3, __uint_as_float(va.y & 0xFFFF0000u));
    e += 2;
  }
  if (e < e1) {
    int sa = csrSrc[e];
    uint2 va = x4[(size_t)sa * 32 + l32];
    m0 = fmaxf(m0, __uint_as_float(va.x << 16));
    m1 = fmaxf(m1, __uint_as_float(va.x & 0xFFFF0000u));
    m2 = fmaxf(m2, __uint_as_float(va.y << 16));
    m3 = fmaxf(m3, __uint_as_float(va.y & 0xFFFF0000u));
  }
  m0 = fmaxf(m0, __shfl_xor(m0, 32, 64));
  m1 = fmaxf(m1, __shfl_xor(m1, 32, 64));
  m2 = fmaxf(m2, __shfl_xor(m2, 32, 64));
  m3 = fmaxf(m3, __shfl_xor(m3, 32, 64));
  uint2 r = make_uint2(0u, 0u);
  if (e0 != e1) {
    r.x = (__float_as_uint(m0) >> 16) | (__float_as_uint(m1) & 0xFFFF0000u);
    r.y = (__float_as_uint(m2) >> 16) | (__float_as_uint(m3) & 0xFFFF0000u);
  }
  if (h == 0) agg4[(size_t)n * 32 + l32] = r;
}

// ================= fused MFMA layer (register-resident B) =================
#define PA 280

__global__ __launch_bounds__(256) void fused_mfma_kernel(
    const unsigned short* __restrict__ aggbf, unsigned short* __restrict__ xbf,
    const unsigned short* __restrict__ Wt, const float* __restrict__ bias,
    float* __restrict__ outF, int nRows, int mode, unsigned kk0, unsigned kk1) {
  __shared__ unsigned short sA[32 * PA];

  const int tid = threadIdx.x;
  const int row0 = blockIdx.x * 32;
  const int wv = tid >> 6, lane = tid & 63;
  const int quad = lane >> 4, m16 = lane & 15;
  const int nbase = wv * 32;

#pragma unroll
  for (int i = 0; i < 4; ++i) {
    int idx = i * 256 + tid;
    int r = idx >> 5;
    int seg = idx & 31;
    uint4 v = make_uint4(0, 0, 0, 0);
    if (row0 + r < nRows) {
      if (seg < 16) v = ((const uint4*)(aggbf + (size_t)(row0 + r) * D))[seg];
      else          v = ((const uint4*)(xbf  + (size_t)(row0 + r) * D))[seg - 16];
    }
    *((uint4*)(sA + r * PA + seg * 8)) = v;
  }

  short8 bfr[2][4][2];
#pragma unroll
  for (int kc = 0; kc < 2; ++kc)
#pragma unroll
    for (int ks = 0; ks < 4; ++ks)
#pragma unroll
      for (int j = 0; j < 2; ++j)
        bfr[kc][ks][j] = *((const short8*)(
            Wt + (size_t)(nbase + j * 16 + m16) * 256 + kc * 128 + ks * 32 + quad * 8));

  floatx4 acc[2][2];
#pragma unroll
  for (int i = 0; i < 2; ++i)
#pragma unroll
    for (int j = 0; j < 2; ++j) acc[i][j] = (floatx4)(0.0f);

  __syncthreads();

#pragma unroll
  for (int kc = 0; kc < 2; ++kc)
#pragma unroll
    for (int ks = 0; ks < 4; ++ks) {
      int kA = kc * 128 + ks * 32 + quad * 8;
      short8 a0 = *((const short8*)(sA + m16 * PA + kA));
      short8 a1 = *((const short8*)(sA + (m16 + 16) * PA + kA));
      acc[0][0] = __builtin_amdgcn_mfma_f32_16x16x32_bf16(a0, bfr[kc][ks][0], acc[0][0], 0, 0, 0);
      acc[0][1] = __builtin_amdgcn_mfma_f32_16x16x32_bf16(a0, bfr[kc][ks][1], acc[0][1], 0, 0, 0);
      acc[1][0] = __builtin_amdgcn_mfma_f32_16x16x32_bf16(a1, bfr[kc][ks][0], acc[1][0], 0, 0, 0);
      acc[1][1] = __builtin_amdgcn_mfma_f32_16x16x32_bf16(a1, bfr[kc][ks][1], acc[1][1], 0, 0, 0);
    }

#pragma unroll
  for (int j = 0; j < 2; ++j) {
    int col = nbase + j * 16 + m16;
    float bc = bias[col];
#pragma unroll
    for (int i = 0; i < 2; ++i) {
#pragma unroll
      for (int reg = 0; reg < 4; ++reg) {
        int r = row0 + i * 16 + quad * 4 + reg;
        if (r >= nRows) continue;
        float v = acc[i][j][reg] + bc;
        if (mode < 2) {
          v = (v > 0.0f) ? v : expm1f(v);
          unsigned jj = (unsigned)r * D + col;
          unsigned y0, y1;
          threefry2x32(kk0, kk1, 0u, jj, y0, y1);
          float u = __uint_as_float((((y0 ^ y1) >> 9)) | 0x3F800000u) - 1.0f;
          v = (u < 0.8f) ? v * 1.25f : 0.0f;
          xbf[(size_t)r * D + col] = f2bf(v);
        } else {
          outF[(size_t)r * D + col] = v;
        }
      }
    }
  }
}

extern "C" void kernel_launch(void* const* d_in, const int* in_sizes, int n_in,
                              void* d_out, int out_size, void* d_ws, size_t ws_size,
                              hipStream_t stream) {
  const float* feat = (const float*)d_in[0];
  const int* ei = (const int*)d_in[1];
  const float* Wl0 = (const float*)d_in[2];
  const float* Wr0 = (const float*)d_in[3];
  const float* b0 = (const float*)d_in[4];
  const float* Wl1 = (const float*)d_in[5];
  const float* Wr1 = (const float*)d_in[6];
  const float* b1 = (const float*)d_in[7];
  const float* Wl2 = (const float*)d_in[8];
  const float* Wr2 = (const float*)d_in[9];
  const float* b2 = (const float*)d_in[10];

  const int N = in_sizes[0] / D;   // 100000
  const int E = in_sizes[1] / 2;   // 1600000
  const int* src = ei;
  const int* dst = ei + E;

  // ---- workspace ----
  const size_t bfBytes = (size_t)N * D * 2;   // 25.6 MB
  char* wsp = (char*)d_ws;
  size_t off = 0;
  unsigned short* xbf   = (unsigned short*)(wsp + off); off += bfBytes;
  unsigned short* aggbf = (unsigned short*)(wsp + off); off += bfBytes;
  unsigned short* Wt    = (unsigned short*)(wsp + off); off += ((size_t)3 * 128 * 256 * 2 + 511) & ~511ull;
  int* rowStart  = (int*)(wsp + off); off += ((size_t)(N + 1) * 4 + 511) & ~511ull;
  int* cursor    = (int*)(wsp + off); off += ((size_t)N * 4 + 511) & ~511ull;
  int* blockSums = (int*)(wsp + off); off += 2048;
  int* bucketCursor = (int*)(wsp + off); off += 4096;
  int* csrSrc    = (int*)(wsp + off); off += (size_t)E * 4;
  uint2* pairs   = (uint2*)(wsp + off); off += (size_t)E * 8;   // 12.8 MB

  const int nChunks = (N + CHUNK - 1) / CHUNK;            // 98
  const int nBuck = (N + (1 << BSHIFT) - 1) >> BSHIFT;    // 196

  // ---- JAX partitionable threefry keys on host ----
  unsigned k1a, k1b, k2a, k2b;
  threefry2x32(0u, 42u, 0u, 0u, k1a, k1b);
  threefry2x32(0u, 42u, 0u, 1u, k2a, k2b);

  // ---- CSR build ----
  hipMemsetAsync(cursor, 0, (size_t)N * 4, stream);
  hist_kernel<<<(E + 255) / 256, 256, 0, stream>>>(dst, cursor, E);
  reduce_chunk_kernel<<<nChunks, 256, 0, stream>>>(cursor, blockSums, N);
  scan_block_sums_kernel<<<1, 64, 0, stream>>>(blockSums, nChunks);
  scan_chunk_kernel<<<nChunks, 256, 0, stream>>>(cursor, blockSums, rowStart, cursor, N);
  init_bucket_cursor_kernel<<<(nBuck + 256) / 256, 256, 0, stream>>>(rowStart, bucketCursor, nBuck, N);
  bucket_scatter_kernel<<<(E + 2047) / 2048, 256, 0, stream>>>(src, dst, bucketCursor, pairs, E, nBuck);
  local_fill_kernel<<<nBuck, 256, 0, stream>>>(pairs, rowStart, cursor, csrSrc, N);

  // ---- prep bf16 ----
  convert_feat_kernel<<<(N * D / 4 + 255) / 256, 256, 0, stream>>>(feat, xbf, N * D);
  pack_weights_kernel<<<(3 * 128 * 256 + 255) / 256, 256, 0, stream>>>(
      Wl0, Wr0, Wl1, Wr1, Wl2, Wr2, Wt);

  dim3 blk(256);
  dim3 grdMax((N + 3) / 4);
  dim3 grdGemm((N + 31) / 32);
  float* outF = (float*)d_out;

  // ---- layer 0 ----
  gather_max_bf16_kernel<<<grdMax, blk, 0, stream>>>((const uint2*)xbf, rowStart, csrSrc, (uint2*)aggbf, N);
  fused_mfma_kernel<<<grdGemm, blk, 0, stream>>>(aggbf, xbf, Wt, b0, outF, N, 0, k1a, k1b);

  // ---- layer 1 ----
  gather_max_bf16_kernel<<<grdMax, blk, 0, stream>>>((const uint2*)xbf, rowStart, csrSrc, (uint2*)aggbf, N);
  fused_mfma_kernel<<<grdGemm, blk, 0, stream>>>(aggbf, xbf, Wt + 32768, b1, outF, N, 1, k2a, k2b);

  // ---- layer 2 (fp32 out) ----
  gather_max_bf16_kernel<<<grdMax, blk, 0, stream>>>((const uint2*)xbf, rowStart, csrSrc, (uint2*)aggbf, N);
  fused_mfma_kernel<<<grdGemm, blk, 0, stream>>>(aggbf, xbf, Wt + 65536, b2, outF, N, 2, 0u, 0u);
}

// Round 8
// 602.330 us; speedup vs baseline: 12.9926x; 1.0228x over previous
//
#include <hip/hip_runtime.h>
#include <math.h>

#define D 128
#define CHUNK 1024
#define BSHIFT 9              // bucket = 512 nodes
#define BCAP 12288            // LDS staging capacity (edges) per bucket

typedef __attribute__((ext_vector_type(8))) short short8;
typedef __attribute__((ext_vector_type(4))) float floatx4;

// ---------------- threefry2x32 (JAX-compatible, 20 rounds) ----------------
__host__ __device__ __forceinline__ unsigned rotl32(unsigned v, int r) {
  return (v << r) | (v >> (32 - r));
}

__host__ __device__ __forceinline__ void threefry2x32(unsigned k0, unsigned k1,
                                                      unsigned x0, unsigned x1,
                                                      unsigned &o0, unsigned &o1) {
  unsigned ks2 = k0 ^ k1 ^ 0x1BD11BDAu;
  unsigned v0 = x0 + k0;
  unsigned v1 = x1 + k1;
  v0 += v1; v1 = rotl32(v1, 13); v1 ^= v0;
  v0 += v1; v1 = rotl32(v1, 15); v1 ^= v0;
  v0 += v1; v1 = rotl32(v1, 26); v1 ^= v0;
  v0 += v1; v1 = rotl32(v1, 6);  v1 ^= v0;
  v0 += k1; v1 += ks2 + 1u;
  v0 += v1; v1 = rotl32(v1, 17); v1 ^= v0;
  v0 += v1; v1 = rotl32(v1, 29); v1 ^= v0;
  v0 += v1; v1 = rotl32(v1, 16); v1 ^= v0;
  v0 += v1; v1 = rotl32(v1, 24); v1 ^= v0;
  v0 += ks2; v1 += k0 + 2u;
  v0 += v1; v1 = rotl32(v1, 13); v1 ^= v0;
  v0 += v1; v1 = rotl32(v1, 15); v1 ^= v0;
  v0 += v1; v1 = rotl32(v1, 26); v1 ^= v0;
  v0 += v1; v1 = rotl32(v1, 6);  v1 ^= v0;
  v0 += k0; v1 += k1 + 3u;
  v0 += v1; v1 = rotl32(v1, 17); v1 ^= v0;
  v0 += v1; v1 = rotl32(v1, 29); v1 ^= v0;
  v0 += v1; v1 = rotl32(v1, 16); v1 ^= v0;
  v0 += v1; v1 = rotl32(v1, 24); v1 ^= v0;
  v0 += k1; v1 += ks2 + 4u;
  v0 += v1; v1 = rotl32(v1, 13); v1 ^= v0;
  v0 += v1; v1 = rotl32(v1, 15); v1 ^= v0;
  v0 += v1; v1 = rotl32(v1, 26); v1 ^= v0;
  v0 += v1; v1 = rotl32(v1, 6);  v1 ^= v0;
  v0 += ks2; v1 += k0 + 5u;
  o0 = v0; o1 = v1;
}

// float -> bf16 (round to nearest even)
__device__ __forceinline__ unsigned short f2bf(float f) {
  unsigned u = __float_as_uint(f);
  unsigned r = u + 0x7FFFu + ((u >> 16) & 1u);
  return (unsigned short)(r >> 16);
}

// ================= CSR build =================
__global__ __launch_bounds__(256) void hist_kernel(
    const int* __restrict__ dst, int* __restrict__ counts, int nEdges) {
  int e = blockIdx.x * 256 + threadIdx.x;
  if (e < nEdges) atomicAdd(&counts[dst[e]], 1);
}

__global__ __launch_bounds__(256) void reduce_chunk_kernel(
    const int* __restrict__ counts, int* __restrict__ blockSums, int nNodes) {
  __shared__ int s[256];
  int t = threadIdx.x;
  int base = blockIdx.x * CHUNK + t * 4;
  int sum = 0;
#pragma unroll
  for (int i = 0; i < 4; ++i)
    if (base + i < nNodes) sum += counts[base + i];
  s[t] = sum;
  __syncthreads();
  for (int off = 128; off > 0; off >>= 1) {
    if (t < off) s[t] += s[t + off];
    __syncthreads();
  }
  if (t == 0) blockSums[blockIdx.x] = s[0];
}

// exclusive-scan blockSums in place (+ total at [n])
__global__ void scan_block_sums_kernel(int* blockSums, int nChunks) {
  if (threadIdx.x == 0 && blockIdx.x == 0) {
    int run = 0;
    for (int i = 0; i < nChunks; ++i) {
      int v = blockSums[i];
      blockSums[i] = run;
      run += v;
    }
    blockSums[nChunks] = run;
  }
}

__global__ __launch_bounds__(256) void scan_chunk_kernel(
    const int* __restrict__ counts, const int* __restrict__ blockOffs,
    int* __restrict__ rowStart, int* __restrict__ cursor, int nNodes) {
  __shared__ int sSum[256];
  int t = threadIdx.x;
  int base = blockIdx.x * CHUNK + t * 4;
  int c0 = 0, c1 = 0, c2 = 0, c3 = 0;
  if (base + 0 < nNodes) c0 = counts[base + 0];
  if (base + 1 < nNodes) c1 = counts[base + 1];
  if (base + 2 < nNodes) c2 = counts[base + 2];
  if (base + 3 < nNodes) c3 = counts[base + 3];
  int local = c0 + c1 + c2 + c3;
  sSum[t] = local;
  __syncthreads();
  for (int off = 1; off < 256; off <<= 1) {
    int v = (t >= off) ? sSum[t - off] : 0;
    __syncthreads();
    sSum[t] += v;
    __syncthreads();
  }
  int excl = blockOffs[blockIdx.x] + sSum[t] - local;
  int p0 = excl, p1 = p0 + c0, p2 = p1 + c1, p3 = p2 + c2;
  if (base + 0 < nNodes) { rowStart[base + 0] = p0; cursor[base + 0] = p0;
                           if (base + 0 == nNodes - 1) rowStart[nNodes] = p1; }
  if (base + 1 < nNodes) { rowStart[base + 1] = p1; cursor[base + 1] = p1;
                           if (base + 1 == nNodes - 1) rowStart[nNodes] = p2; }
  if (base + 2 < nNodes) { rowStart[base + 2] = p2; cursor[base + 2] = p2;
                           if (base + 2 == nNodes - 1) rowStart[nNodes] = p3; }
  if (base + 3 < nNodes) { rowStart[base + 3] = p3; cursor[base + 3] = p3;
                           if (base + 3 == nNodes - 1) rowStart[nNodes] = p3 + c3; }
}

// bucketCursor[b] = rowStart[min(b*512, N)] -> pairs regions == CSR regions
__global__ void init_bucket_cursor_kernel(
    const int* __restrict__ rowStart, int* __restrict__ bucketCursor,
    int nBuck, int nNodes) {
  int b = blockIdx.x * 256 + threadIdx.x;
  if (b <= nBuck) {
    int n = b << BSHIFT;
    if (n > nNodes) n = nNodes;
    bucketCursor[b] = rowStart[n];
  }
}

// ---- two-level bucketed edge partition (kills write-allocate waste) ----
// 4096 edges per block -> longer per-bucket append runs (less partial-line WA)
__global__ __launch_bounds__(256) void bucket_scatter_kernel(
    const int* __restrict__ src, const int* __restrict__ dst,
    int* __restrict__ bucketCursor, uint2* __restrict__ pairs,
    int nEdges, int nBuck) {
  __shared__ int lcount[256];
  __shared__ int lbase[256];
  __shared__ int loff[256];
  int t = threadIdx.x;
  lcount[t] = 0; loff[t] = 0;
  __syncthreads();
  int e0 = blockIdx.x * 4096;
  for (int i = t; i < 4096; i += 256) {
    int e = e0 + i;
    if (e < nEdges) atomicAdd(&lcount[dst[e] >> BSHIFT], 1);
  }
  __syncthreads();
  if (t < nBuck) {
    int c = lcount[t];
    if (c > 0) lbase[t] = atomicAdd(&bucketCursor[t], c);
  }
  __syncthreads();
  for (int i = t; i < 4096; i += 256) {
    int e = e0 + i;
    if (e < nEdges) {
      int d = dst[e];
      int b = d >> BSHIFT;
      int lp = atomicAdd(&loff[b], 1);
      pairs[lbase[b] + lp] = make_uint2((unsigned)src[e], (unsigned)d);
    }
  }
}

// One block per bucket: scatter src into LDS staging via LDS atomics, then
// stream out contiguously (single-writer, full-line writes -> no WA waste).
__global__ __launch_bounds__(256) void local_fill_kernel(
    const uint2* __restrict__ pairs, const int* __restrict__ rowStart,
    int* __restrict__ cursor, int* __restrict__ csrSrc, int nNodes) {
  __shared__ int sData[BCAP];           // 48 KB
  __shared__ int lcur[1 << BSHIFT];     // 2 KB
  int b = blockIdx.x;
  int node0 = b << BSHIFT;
  int node1 = node0 + (1 << BSHIFT);
  if (node1 > nNodes) node1 = nNodes;
  int base = rowStart[node0];
  int end = rowStart[node1];
  int cnt = end - base;
  int t = threadIdx.x;
  for (int i = t; i < node1 - node0; i += 256)
    lcur[i] = rowStart[node0 + i] - base;
  __syncthreads();
  if (cnt <= BCAP) {
    for (int i = base + t; i < end; i += 256) {
      uint2 p = pairs[i];
      int lp = atomicAdd(&lcur[p.y - (unsigned)node0], 1);
      sData[lp] = (int)p.x;
    }
    __syncthreads();
    for (int i = t; i < cnt; i += 256)
      csrSrc[base + i] = sData[i];
  } else {
    // deterministic-capacity fallback (never expected for this dataset)
    for (int i = base + t; i < end; i += 256) {
      uint2 p = pairs[i];
      int pos = atomicAdd(&cursor[p.y], 1);
      csrSrc[pos] = (int)p.x;
    }
  }
}

// ================= prep: fp32 -> bf16 =================
__global__ __launch_bounds__(256) void convert_feat_kernel(
    const float* __restrict__ f, unsigned short* __restrict__ o, int nElems) {
  int i = (blockIdx.x * 256 + threadIdx.x) * 4;
  if (i + 3 < nElems) {
    float4 v = *((const float4*)(f + i));
    unsigned a = (unsigned)f2bf(v.x) | ((unsigned)f2bf(v.y) << 16);
    unsigned b = (unsigned)f2bf(v.z) | ((unsigned)f2bf(v.w) << 16);
    *((uint2*)(o + i)) = make_uint2(a, b);
  } else {
    for (int j = i; j < nElems; ++j) o[j] = f2bf(f[j]);
  }
}

// Wt[l][n][k] bf16, k<128 from Wl[k][n], k>=128 from Wr[k-128][n]
__global__ __launch_bounds__(256) void pack_weights_kernel(
    const float* __restrict__ Wl0, const float* __restrict__ Wr0,
    const float* __restrict__ Wl1, const float* __restrict__ Wr1,
    const float* __restrict__ Wl2, const float* __restrict__ Wr2,
    unsigned short* __restrict__ Wt) {
  int t = blockIdx.x * 256 + threadIdx.x;
  if (t >= 3 * 128 * 256) return;
  int l = t >> 15;
  int rem = t & 32767;
  int n = rem >> 8;
  int k = rem & 255;
  const float* Wl = (l == 0) ? Wl0 : (l == 1) ? Wl1 : Wl2;
  const float* Wr = (l == 0) ? Wr0 : (l == 1) ? Wr1 : Wr2;
  float v = (k < 128) ? Wl[k * D + n] : Wr[(k - 128) * D + n];
  Wt[t] = f2bf(v);
}

// ================= gather segment-max on bf16 rows =================
// One wave per node. 16 B/lane: 16 lanes cover a 256 B row; the four 16-lane
// quarters take different edges -> 8 edges per iter from 2 loads/lane.
__device__ __forceinline__ void maxpack(float m[8], uint4 v) {
  m[0] = fmaxf(m[0], __uint_as_float(v.x << 16));
  m[1] = fmaxf(m[1], __uint_as_float(v.x & 0xFFFF0000u));
  m[2] = fmaxf(m[2], __uint_as_float(v.y << 16));
  m[3] = fmaxf(m[3], __uint_as_float(v.y & 0xFFFF0000u));
  m[4] = fmaxf(m[4], __uint_as_float(v.z << 16));
  m[5] = fmaxf(m[5], __uint_as_float(v.z & 0xFFFF0000u));
  m[6] = fmaxf(m[6], __uint_as_float(v.w << 16));
  m[7] = fmaxf(m[7], __uint_as_float(v.w & 0xFFFF0000u));
}

__global__ __launch_bounds__(256) void gather_max_bf16_kernel(
    const uint4* __restrict__ x8, const int* __restrict__ rowStart,
    const int* __restrict__ csrSrc, uint4* __restrict__ agg8, int nNodes) {
  int n = blockIdx.x * 4 + (threadIdx.x >> 6);
  if (n >= nNodes) return;
  int lane = threadIdx.x & 63;
  int q = lane >> 4;        // quarter: which edge of a group of 4
  int l16 = lane & 15;      // 16-byte segment within the row
  int e0 = rowStart[n], e1 = rowStart[n + 1];
  float m[8];
#pragma unroll
  for (int i = 0; i < 8; ++i) m[i] = -INFINITY;
  int e = e0;
  for (; e + 7 < e1; e += 8) {
    int sa = csrSrc[e + q];
    int sb = csrSrc[e + 4 + q];
    uint4 va = x8[(size_t)sa * 16 + l16];
    uint4 vb = x8[(size_t)sb * 16 + l16];
    maxpack(m, va);
    maxpack(m, vb);
  }
  if (e + 3 < e1) {
    int sa = csrSrc[e + q];
    uint4 va = x8[(size_t)sa * 16 + l16];
    maxpack(m, va);
    e += 4;
  }
  for (; e < e1; ++e) {     // <4 leftover: all quarters read same row (coalesced)
    int sa = csrSrc[e];
    uint4 va = x8[(size_t)sa * 16 + l16];
    maxpack(m, va);
  }
  // combine the four quarters
#pragma unroll
  for (int i = 0; i < 8; ++i) {
    m[i] = fmaxf(m[i], __shfl_xor(m[i], 16, 64));
    m[i] = fmaxf(m[i], __shfl_xor(m[i], 32, 64));
  }
  uint4 r = make_uint4(0u, 0u, 0u, 0u);  // isolated node -> +0.0
  if (e0 != e1) {
    r.x = (__float_as_uint(m[0]) >> 16) | (__float_as_uint(m[1]) & 0xFFFF0000u);
    r.y = (__float_as_uint(m[2]) >> 16) | (__float_as_uint(m[3]) & 0xFFFF0000u);
    r.z = (__float_as_uint(m[4]) >> 16) | (__float_as_uint(m[5]) & 0xFFFF0000u);
    r.w = (__float_as_uint(m[6]) >> 16) | (__float_as_uint(m[7]) & 0xFFFF0000u);
  }
  if (q == 0) agg8[(size_t)n * 16 + l16] = r;
}

// ================= fused MFMA layer (register-resident B) =================
#define PA 280

__global__ __launch_bounds__(256) void fused_mfma_kernel(
    const unsigned short* __restrict__ aggbf, unsigned short* __restrict__ xbf,
    const unsigned short* __restrict__ Wt, const float* __restrict__ bias,
    float* __restrict__ outF, int nRows, int mode, unsigned kk0, unsigned kk1) {
  __shared__ unsigned short sA[32 * PA];

  const int tid = threadIdx.x;
  const int row0 = blockIdx.x * 32;
  const int wv = tid >> 6, lane = tid & 63;
  const int quad = lane >> 4, m16 = lane & 15;
  const int nbase = wv * 32;

#pragma unroll
  for (int i = 0; i < 4; ++i) {
    int idx = i * 256 + tid;
    int r = idx >> 5;
    int seg = idx & 31;
    uint4 v = make_uint4(0, 0, 0, 0);
    if (row0 + r < nRows) {
      if (seg < 16) v = ((const uint4*)(aggbf + (size_t)(row0 + r) * D))[seg];
      else          v = ((const uint4*)(xbf  + (size_t)(row0 + r) * D))[seg - 16];
    }
    *((uint4*)(sA + r * PA + seg * 8)) = v;
  }

  short8 bfr[2][4][2];
#pragma unroll
  for (int kc = 0; kc < 2; ++kc)
#pragma unroll
    for (int ks = 0; ks < 4; ++ks)
#pragma unroll
      for (int j = 0; j < 2; ++j)
        bfr[kc][ks][j] = *((const short8*)(
            Wt + (size_t)(nbase + j * 16 + m16) * 256 + kc * 128 + ks * 32 + quad * 8));

  floatx4 acc[2][2];
#pragma unroll
  for (int i = 0; i < 2; ++i)
#pragma unroll
    for (int j = 0; j < 2; ++j) acc[i][j] = (floatx4)(0.0f);

  __syncthreads();

#pragma unroll
  for (int kc = 0; kc < 2; ++kc)
#pragma unroll
    for (int ks = 0; ks < 4; ++ks) {
      int kA = kc * 128 + ks * 32 + quad * 8;
      short8 a0 = *((const short8*)(sA + m16 * PA + kA));
      short8 a1 = *((const short8*)(sA + (m16 + 16) * PA + kA));
      acc[0][0] = __builtin_amdgcn_mfma_f32_16x16x32_bf16(a0, bfr[kc][ks][0], acc[0][0], 0, 0, 0);
      acc[0][1] = __builtin_amdgcn_mfma_f32_16x16x32_bf16(a0, bfr[kc][ks][1], acc[0][1], 0, 0, 0);
      acc[1][0] = __builtin_amdgcn_mfma_f32_16x16x32_bf16(a1, bfr[kc][ks][0], acc[1][0], 0, 0, 0);
      acc[1][1] = __builtin_amdgcn_mfma_f32_16x16x32_bf16(a1, bfr[kc][ks][1], acc[1][1], 0, 0, 0);
    }

#pragma unroll
  for (int j = 0; j < 2; ++j) {
    int col = nbase + j * 16 + m16;
    float bc = bias[col];
#pragma unroll
    for (int i = 0; i < 2; ++i) {
#pragma unroll
      for (int reg = 0; reg < 4; ++reg) {
        int r = row0 + i * 16 + quad * 4 + reg;
        if (r >= nRows) continue;
        float v = acc[i][j][reg] + bc;
        if (mode < 2) {
          v = (v > 0.0f) ? v : expm1f(v);
          unsigned jj = (unsigned)r * D + col;
          unsigned y0, y1;
          threefry2x32(kk0, kk1, 0u, jj, y0, y1);
          float u = __uint_as_float((((y0 ^ y1) >> 9)) | 0x3F800000u) - 1.0f;
          v = (u < 0.8f) ? v * 1.25f : 0.0f;
          xbf[(size_t)r * D + col] = f2bf(v);
        } else {
          outF[(size_t)r * D + col] = v;
        }
      }
    }
  }
}

extern "C" void kernel_launch(void* const* d_in, const int* in_sizes, int n_in,
                              void* d_out, int out_size, void* d_ws, size_t ws_size,
                              hipStream_t stream) {
  const float* feat = (const float*)d_in[0];
  const int* ei = (const int*)d_in[1];
  const float* Wl0 = (const float*)d_in[2];
  const float* Wr0 = (const float*)d_in[3];
  const float* b0 = (const float*)d_in[4];
  const float* Wl1 = (const float*)d_in[5];
  const float* Wr1 = (const float*)d_in[6];
  const float* b1 = (const float*)d_in[7];
  const float* Wl2 = (const float*)d_in[8];
  const float* Wr2 = (const float*)d_in[9];
  const float* b2 = (const float*)d_in[10];

  const int N = in_sizes[0] / D;   // 100000
  const int E = in_sizes[1] / 2;   // 1600000
  const int* src = ei;
  const int* dst = ei + E;

  // ---- workspace ----
  const size_t bfBytes = (size_t)N * D * 2;   // 25.6 MB
  char* wsp = (char*)d_ws;
  size_t off = 0;
  unsigned short* xbf   = (unsigned short*)(wsp + off); off += bfBytes;
  unsigned short* aggbf = (unsigned short*)(wsp + off); off += bfBytes;
  unsigned short* Wt    = (unsigned short*)(wsp + off); off += ((size_t)3 * 128 * 256 * 2 + 511) & ~511ull;
  int* rowStart  = (int*)(wsp + off); off += ((size_t)(N + 1) * 4 + 511) & ~511ull;
  int* cursor    = (int*)(wsp + off); off += ((size_t)N * 4 + 511) & ~511ull;
  int* blockSums = (int*)(wsp + off); off += 2048;
  int* bucketCursor = (int*)(wsp + off); off += 4096;
  int* csrSrc    = (int*)(wsp + off); off += (size_t)E * 4;
  uint2* pairs   = (uint2*)(wsp + off); off += (size_t)E * 8;   // 12.8 MB

  const int nChunks = (N + CHUNK - 1) / CHUNK;            // 98
  const int nBuck = (N + (1 << BSHIFT) - 1) >> BSHIFT;    // 196

  // ---- JAX partitionable threefry keys on host ----
  unsigned k1a, k1b, k2a, k2b;
  threefry2x32(0u, 42u, 0u, 0u, k1a, k1b);
  threefry2x32(0u, 42u, 0u, 1u, k2a, k2b);

  // ---- CSR build ----
  hipMemsetAsync(cursor, 0, (size_t)N * 4, stream);
  hist_kernel<<<(E + 255) / 256, 256, 0, stream>>>(dst, cursor, E);
  reduce_chunk_kernel<<<nChunks, 256, 0, stream>>>(cursor, blockSums, N);
  scan_block_sums_kernel<<<1, 64, 0, stream>>>(blockSums, nChunks);
  scan_chunk_kernel<<<nChunks, 256, 0, stream>>>(cursor, blockSums, rowStart, cursor, N);
  init_bucket_cursor_kernel<<<(nBuck + 256) / 256, 256, 0, stream>>>(rowStart, bucketCursor, nBuck, N);
  bucket_scatter_kernel<<<(E + 4095) / 4096, 256, 0, stream>>>(src, dst, bucketCursor, pairs, E, nBuck);
  local_fill_kernel<<<nBuck, 256, 0, stream>>>(pairs, rowStart, cursor, csrSrc, N);

  // ---- prep bf16 ----
  convert_feat_kernel<<<(N * D / 4 + 255) / 256, 256, 0, stream>>>(feat, xbf, N * D);
  pack_weights_kernel<<<(3 * 128 * 256 + 255) / 256, 256, 0, stream>>>(
      Wl0, Wr0, Wl1, Wr1, Wl2, Wr2, Wt);

  dim3 blk(256);
  dim3 grdMax((N + 3) / 4);
  dim3 grdGemm((N + 31) / 32);
  float* outF = (float*)d_out;

  // ---- layer 0 ----
  gather_max_bf16_kernel<<<grdMax, blk, 0, stream>>>((const uint4*)xbf, rowStart, csrSrc, (uint4*)aggbf, N);
  fused_mfma_kernel<<<grdGemm, blk, 0, stream>>>(aggbf, xbf, Wt, b0, outF, N, 0, k1a, k1b);

  // ---- layer 1 ----
  gather_max_bf16_kernel<<<grdMax, blk, 0, stream>>>((const uint4*)xbf, rowStart, csrSrc, (uint4*)aggbf, N);
  fused_mfma_kernel<<<grdGemm, blk, 0, stream>>>(aggbf, xbf, Wt + 32768, b1, outF, N, 1, k2a, k2b);

  // ---- layer 2 (fp32 out) ----
  gather_max_bf16_kernel<<<grdMax, blk, 0, stream>>>((const uint4*)xbf, rowStart, csrSrc, (uint4*)aggbf, N);
  fused_mfma_kernel<<<grdGemm, blk, 0, stream>>>(aggbf, xbf, Wt + 65536, b2, outF, N, 2, 0u, 0u);
}

// Round 9
// 589.339 us; speedup vs baseline: 13.2790x; 1.0220x over previous
//
#include <hip/hip_runtime.h>
#include <math.h>

#define D 128
#define CHUNK 1024
#define BSHIFT 9              // bucket = 512 nodes
#define BCAP 12288            // LDS staging capacity (edges) per bucket

typedef __attribute__((ext_vector_type(8))) _Float16 half8;
typedef __attribute__((ext_vector_type(4))) float floatx4;

// ---------------- threefry2x32 (JAX-compatible, 20 rounds) ----------------
__host__ __device__ __forceinline__ unsigned rotl32(unsigned v, int r) {
  return (v << r) | (v >> (32 - r));
}

__host__ __device__ __forceinline__ void threefry2x32(unsigned k0, unsigned k1,
                                                      unsigned x0, unsigned x1,
                                                      unsigned &o0, unsigned &o1) {
  unsigned ks2 = k0 ^ k1 ^ 0x1BD11BDAu;
  unsigned v0 = x0 + k0;
  unsigned v1 = x1 + k1;
  v0 += v1; v1 = rotl32(v1, 13); v1 ^= v0;
  v0 += v1; v1 = rotl32(v1, 15); v1 ^= v0;
  v0 += v1; v1 = rotl32(v1, 26); v1 ^= v0;
  v0 += v1; v1 = rotl32(v1, 6);  v1 ^= v0;
  v0 += k1; v1 += ks2 + 1u;
  v0 += v1; v1 = rotl32(v1, 17); v1 ^= v0;
  v0 += v1; v1 = rotl32(v1, 29); v1 ^= v0;
  v0 += v1; v1 = rotl32(v1, 16); v1 ^= v0;
  v0 += v1; v1 = rotl32(v1, 24); v1 ^= v0;
  v0 += ks2; v1 += k0 + 2u;
  v0 += v1; v1 = rotl32(v1, 13); v1 ^= v0;
  v0 += v1; v1 = rotl32(v1, 15); v1 ^= v0;
  v0 += v1; v1 = rotl32(v1, 26); v1 ^= v0;
  v0 += v1; v1 = rotl32(v1, 6);  v1 ^= v0;
  v0 += k0; v1 += k1 + 3u;
  v0 += v1; v1 = rotl32(v1, 17); v1 ^= v0;
  v0 += v1; v1 = rotl32(v1, 29); v1 ^= v0;
  v0 += v1; v1 = rotl32(v1, 16); v1 ^= v0;
  v0 += v1; v1 = rotl32(v1, 24); v1 ^= v0;
  v0 += k1; v1 += ks2 + 4u;
  v0 += v1; v1 = rotl32(v1, 13); v1 ^= v0;
  v0 += v1; v1 = rotl32(v1, 15); v1 ^= v0;
  v0 += v1; v1 = rotl32(v1, 26); v1 ^= v0;
  v0 += v1; v1 = rotl32(v1, 6);  v1 ^= v0;
  v0 += ks2; v1 += k0 + 5u;
  o0 = v0; o1 = v1;
}

// float -> fp16 bits (RNE via v_cvt_f16_f32)
__device__ __forceinline__ unsigned short f2h(float f) {
  _Float16 h = (_Float16)f;
  return *(unsigned short*)&h;
}

// packed fp16 max (VOP3P, 1 instr for 2 elements)
__device__ __forceinline__ unsigned pkmax(unsigned a, unsigned b) {
  unsigned r;
  asm("v_pk_max_f16 %0, %1, %2" : "=v"(r) : "v"(a), "v"(b));
  return r;
}

// ================= CSR build =================
__global__ __launch_bounds__(256) void hist_kernel(
    const int* __restrict__ dst, int* __restrict__ counts, int nEdges) {
  int e = blockIdx.x * 256 + threadIdx.x;
  if (e < nEdges) atomicAdd(&counts[dst[e]], 1);
}

__global__ __launch_bounds__(256) void reduce_chunk_kernel(
    const int* __restrict__ counts, int* __restrict__ blockSums, int nNodes) {
  __shared__ int s[256];
  int t = threadIdx.x;
  int base = blockIdx.x * CHUNK + t * 4;
  int sum = 0;
#pragma unroll
  for (int i = 0; i < 4; ++i)
    if (base + i < nNodes) sum += counts[base + i];
  s[t] = sum;
  __syncthreads();
  for (int off = 128; off > 0; off >>= 1) {
    if (t < off) s[t] += s[t + off];
    __syncthreads();
  }
  if (t == 0) blockSums[blockIdx.x] = s[0];
}

// exclusive-scan blockSums in place (+ total at [n])
__global__ void scan_block_sums_kernel(int* blockSums, int nChunks) {
  if (threadIdx.x == 0 && blockIdx.x == 0) {
    int run = 0;
    for (int i = 0; i < nChunks; ++i) {
      int v = blockSums[i];
      blockSums[i] = run;
      run += v;
    }
    blockSums[nChunks] = run;
  }
}

__global__ __launch_bounds__(256) void scan_chunk_kernel(
    const int* __restrict__ counts, const int* __restrict__ blockOffs,
    int* __restrict__ rowStart, int* __restrict__ cursor, int nNodes) {
  __shared__ int sSum[256];
  int t = threadIdx.x;
  int base = blockIdx.x * CHUNK + t * 4;
  int c0 = 0, c1 = 0, c2 = 0, c3 = 0;
  if (base + 0 < nNodes) c0 = counts[base + 0];
  if (base + 1 < nNodes) c1 = counts[base + 1];
  if (base + 2 < nNodes) c2 = counts[base + 2];
  if (base + 3 < nNodes) c3 = counts[base + 3];
  int local = c0 + c1 + c2 + c3;
  sSum[t] = local;
  __syncthreads();
  for (int off = 1; off < 256; off <<= 1) {
    int v = (t >= off) ? sSum[t - off] : 0;
    __syncthreads();
    sSum[t] += v;
    __syncthreads();
  }
  int excl = blockOffs[blockIdx.x] + sSum[t] - local;
  int p0 = excl, p1 = p0 + c0, p2 = p1 + c1, p3 = p2 + c2;
  if (base + 0 < nNodes) { rowStart[base + 0] = p0; cursor[base + 0] = p0;
                           if (base + 0 == nNodes - 1) rowStart[nNodes] = p1; }
  if (base + 1 < nNodes) { rowStart[base + 1] = p1; cursor[base + 1] = p1;
                           if (base + 1 == nNodes - 1) rowStart[nNodes] = p2; }
  if (base + 2 < nNodes) { rowStart[base + 2] = p2; cursor[base + 2] = p2;
                           if (base + 2 == nNodes - 1) rowStart[nNodes] = p3; }
  if (base + 3 < nNodes) { rowStart[base + 3] = p3; cursor[base + 3] = p3;
                           if (base + 3 == nNodes - 1) rowStart[nNodes] = p3 + c3; }
}

// bucketCursor[b] = rowStart[min(b*512, N)] -> pairs regions == CSR regions
__global__ void init_bucket_cursor_kernel(
    const int* __restrict__ rowStart, int* __restrict__ bucketCursor,
    int nBuck, int nNodes) {
  int b = blockIdx.x * 256 + threadIdx.x;
  if (b <= nBuck) {
    int n = b << BSHIFT;
    if (n > nNodes) n = nNodes;
    bucketCursor[b] = rowStart[n];
  }
}

// ---- two-level bucketed edge partition (kills write-allocate waste) ----
__global__ __launch_bounds__(256) void bucket_scatter_kernel(
    const int* __restrict__ src, const int* __restrict__ dst,
    int* __restrict__ bucketCursor, uint2* __restrict__ pairs,
    int nEdges, int nBuck) {
  __shared__ int lcount[256];
  __shared__ int lbase[256];
  __shared__ int loff[256];
  int t = threadIdx.x;
  lcount[t] = 0; loff[t] = 0;
  __syncthreads();
  int e0 = blockIdx.x * 4096;
  for (int i = t; i < 4096; i += 256) {
    int e = e0 + i;
    if (e < nEdges) atomicAdd(&lcount[dst[e] >> BSHIFT], 1);
  }
  __syncthreads();
  if (t < nBuck) {
    int c = lcount[t];
    if (c > 0) lbase[t] = atomicAdd(&bucketCursor[t], c);
  }
  __syncthreads();
  for (int i = t; i < 4096; i += 256) {
    int e = e0 + i;
    if (e < nEdges) {
      int d = dst[e];
      int b = d >> BSHIFT;
      int lp = atomicAdd(&loff[b], 1);
      pairs[lbase[b] + lp] = make_uint2((unsigned)src[e], (unsigned)d);
    }
  }
}

// One block per bucket: LDS-staged single-writer CSR slice fill.
__global__ __launch_bounds__(256) void local_fill_kernel(
    const uint2* __restrict__ pairs, const int* __restrict__ rowStart,
    int* __restrict__ cursor, int* __restrict__ csrSrc, int nNodes) {
  __shared__ int sData[BCAP];           // 48 KB
  __shared__ int lcur[1 << BSHIFT];     // 2 KB
  int b = blockIdx.x;
  int node0 = b << BSHIFT;
  int node1 = node0 + (1 << BSHIFT);
  if (node1 > nNodes) node1 = nNodes;
  int base = rowStart[node0];
  int end = rowStart[node1];
  int cnt = end - base;
  int t = threadIdx.x;
  for (int i = t; i < node1 - node0; i += 256)
    lcur[i] = rowStart[node0 + i] - base;
  __syncthreads();
  if (cnt <= BCAP) {
    for (int i = base + t; i < end; i += 256) {
      uint2 p = pairs[i];
      int lp = atomicAdd(&lcur[p.y - (unsigned)node0], 1);
      sData[lp] = (int)p.x;
    }
    __syncthreads();
    for (int i = t; i < cnt; i += 256)
      csrSrc[base + i] = sData[i];
  } else {
    for (int i = base + t; i < end; i += 256) {
      uint2 p = pairs[i];
      int pos = atomicAdd(&cursor[p.y], 1);
      csrSrc[pos] = (int)p.x;
    }
  }
}

// ================= prep: fp32 -> fp16 =================
__global__ __launch_bounds__(256) void convert_feat_kernel(
    const float* __restrict__ f, unsigned short* __restrict__ o, int nElems) {
  int i = (blockIdx.x * 256 + threadIdx.x) * 4;
  if (i + 3 < nElems) {
    float4 v = *((const float4*)(f + i));
    unsigned a = (unsigned)f2h(v.x) | ((unsigned)f2h(v.y) << 16);
    unsigned b = (unsigned)f2h(v.z) | ((unsigned)f2h(v.w) << 16);
    *((uint2*)(o + i)) = make_uint2(a, b);
  } else {
    for (int j = i; j < nElems; ++j) o[j] = f2h(f[j]);
  }
}

// Wt[l][n][k] fp16, k<128 from Wl[k][n], k>=128 from Wr[k-128][n]
__global__ __launch_bounds__(256) void pack_weights_kernel(
    const float* __restrict__ Wl0, const float* __restrict__ Wr0,
    const float* __restrict__ Wl1, const float* __restrict__ Wr1,
    const float* __restrict__ Wl2, const float* __restrict__ Wr2,
    unsigned short* __restrict__ Wt) {
  int t = blockIdx.x * 256 + threadIdx.x;
  if (t >= 3 * 128 * 256) return;
  int l = t >> 15;
  int rem = t & 32767;
  int n = rem >> 8;
  int k = rem & 255;
  const float* Wl = (l == 0) ? Wl0 : (l == 1) ? Wl1 : Wl2;
  const float* Wr = (l == 0) ? Wr0 : (l == 1) ? Wr1 : Wr2;
  float v = (k < 128) ? Wl[k * D + n] : Wr[(k - 128) * D + n];
  Wt[t] = f2h(v);
}

// ================= gather segment-max on fp16 rows =================
// One wave per node. 16 B/lane: 16 lanes cover a 256 B row; four 16-lane
// quarters take different edges -> 8 edges/iter from 2 loads/lane.
// Accumulators stay PACKED fp16 pairs: 4 x v_pk_max_f16 per 16 B (no unpack).
__global__ __launch_bounds__(256) void gather_max_f16_kernel(
    const uint4* __restrict__ x8, const int* __restrict__ rowStart,
    const int* __restrict__ csrSrc, uint4* __restrict__ agg8, int nNodes) {
  int n = blockIdx.x * 4 + (threadIdx.x >> 6);
  if (n >= nNodes) return;
  int lane = threadIdx.x & 63;
  int q = lane >> 4;        // quarter: which edge of a group of 4
  int l16 = lane & 15;      // 16-byte segment within the row
  int e0 = rowStart[n], e1 = rowStart[n + 1];
  unsigned m0 = 0xFC00FC00u, m1 = 0xFC00FC00u,  // packed fp16 -inf
           m2 = 0xFC00FC00u, m3 = 0xFC00FC00u;
  int e = e0;
  for (; e + 7 < e1; e += 8) {
    int sa = csrSrc[e + q];
    int sb = csrSrc[e + 4 + q];
    uint4 va = x8[(size_t)sa * 16 + l16];
    uint4 vb = x8[(size_t)sb * 16 + l16];
    m0 = pkmax(m0, pkmax(va.x, vb.x));
    m1 = pkmax(m1, pkmax(va.y, vb.y));
    m2 = pkmax(m2, pkmax(va.z, vb.z));
    m3 = pkmax(m3, pkmax(va.w, vb.w));
  }
  if (e + 3 < e1) {
    int sa = csrSrc[e + q];
    uint4 va = x8[(size_t)sa * 16 + l16];
    m0 = pkmax(m0, va.x); m1 = pkmax(m1, va.y);
    m2 = pkmax(m2, va.z); m3 = pkmax(m3, va.w);
    e += 4;
  }
  for (; e < e1; ++e) {     // <4 leftover: all quarters read same row (coalesced)
    int sa = csrSrc[e];
    uint4 va = x8[(size_t)sa * 16 + l16];
    m0 = pkmax(m0, va.x); m1 = pkmax(m1, va.y);
    m2 = pkmax(m2, va.z); m3 = pkmax(m3, va.w);
  }
  // combine the four quarters (packed shuffles)
  m0 = pkmax(m0, (unsigned)__shfl_xor((int)m0, 16, 64));
  m1 = pkmax(m1, (unsigned)__shfl_xor((int)m1, 16, 64));
  m2 = pkmax(m2, (unsigned)__shfl_xor((int)m2, 16, 64));
  m3 = pkmax(m3, (unsigned)__shfl_xor((int)m3, 16, 64));
  m0 = pkmax(m0, (unsigned)__shfl_xor((int)m0, 32, 64));
  m1 = pkmax(m1, (unsigned)__shfl_xor((int)m1, 32, 64));
  m2 = pkmax(m2, (unsigned)__shfl_xor((int)m2, 32, 64));
  m3 = pkmax(m3, (unsigned)__shfl_xor((int)m3, 32, 64));
  uint4 r = make_uint4(0u, 0u, 0u, 0u);  // isolated node -> +0.0
  if (e0 != e1) r = make_uint4(m0, m1, m2, m3);
  if (q == 0) agg8[(size_t)n * 16 + l16] = r;
}

// ================= fused MFMA layer (register-resident B, fp16) =================
#define PA 280

__global__ __launch_bounds__(256) void fused_mfma_kernel(
    const unsigned short* __restrict__ agghf, unsigned short* __restrict__ xhf,
    const unsigned short* __restrict__ Wt, const float* __restrict__ bias,
    float* __restrict__ outF, int nRows, int mode, unsigned kk0, unsigned kk1) {
  __shared__ unsigned short sA[32 * PA];

  const int tid = threadIdx.x;
  const int row0 = blockIdx.x * 32;
  const int wv = tid >> 6, lane = tid & 63;
  const int quad = lane >> 4, m16 = lane & 15;
  const int nbase = wv * 32;

#pragma unroll
  for (int i = 0; i < 4; ++i) {
    int idx = i * 256 + tid;
    int r = idx >> 5;
    int seg = idx & 31;
    uint4 v = make_uint4(0, 0, 0, 0);
    if (row0 + r < nRows) {
      if (seg < 16) v = ((const uint4*)(agghf + (size_t)(row0 + r) * D))[seg];
      else          v = ((const uint4*)(xhf  + (size_t)(row0 + r) * D))[seg - 16];
    }
    *((uint4*)(sA + r * PA + seg * 8)) = v;
  }

  half8 bfr[2][4][2];
#pragma unroll
  for (int kc = 0; kc < 2; ++kc)
#pragma unroll
    for (int ks = 0; ks < 4; ++ks)
#pragma unroll
      for (int j = 0; j < 2; ++j)
        bfr[kc][ks][j] = *((const half8*)(
            Wt + (size_t)(nbase + j * 16 + m16) * 256 + kc * 128 + ks * 32 + quad * 8));

  floatx4 acc[2][2];
#pragma unroll
  for (int i = 0; i < 2; ++i)
#pragma unroll
    for (int j = 0; j < 2; ++j) acc[i][j] = (floatx4)(0.0f);

  __syncthreads();

#pragma unroll
  for (int kc = 0; kc < 2; ++kc)
#pragma unroll
    for (int ks = 0; ks < 4; ++ks) {
      int kA = kc * 128 + ks * 32 + quad * 8;
      half8 a0 = *((const half8*)(sA + m16 * PA + kA));
      half8 a1 = *((const half8*)(sA + (m16 + 16) * PA + kA));
      acc[0][0] = __builtin_amdgcn_mfma_f32_16x16x32_f16(a0, bfr[kc][ks][0], acc[0][0], 0, 0, 0);
      acc[0][1] = __builtin_amdgcn_mfma_f32_16x16x32_f16(a0, bfr[kc][ks][1], acc[0][1], 0, 0, 0);
      acc[1][0] = __builtin_amdgcn_mfma_f32_16x16x32_f16(a1, bfr[kc][ks][0], acc[1][0], 0, 0, 0);
      acc[1][1] = __builtin_amdgcn_mfma_f32_16x16x32_f16(a1, bfr[kc][ks][1], acc[1][1], 0, 0, 0);
    }

#pragma unroll
  for (int j = 0; j < 2; ++j) {
    int col = nbase + j * 16 + m16;
    float bc = bias[col];
#pragma unroll
    for (int i = 0; i < 2; ++i) {
#pragma unroll
      for (int reg = 0; reg < 4; ++reg) {
        int r = row0 + i * 16 + quad * 4 + reg;
        if (r >= nRows) continue;
        float v = acc[i][j][reg] + bc;
        if (mode < 2) {
          v = (v > 0.0f) ? v : expm1f(v);
          unsigned jj = (unsigned)r * D + col;
          unsigned y0, y1;
          threefry2x32(kk0, kk1, 0u, jj, y0, y1);
          float u = __uint_as_float((((y0 ^ y1) >> 9)) | 0x3F800000u) - 1.0f;
          v = (u < 0.8f) ? v * 1.25f : 0.0f;
          xhf[(size_t)r * D + col] = f2h(v);
        } else {
          outF[(size_t)r * D + col] = v;
        }
      }
    }
  }
}

extern "C" void kernel_launch(void* const* d_in, const int* in_sizes, int n_in,
                              void* d_out, int out_size, void* d_ws, size_t ws_size,
                              hipStream_t stream) {
  const float* feat = (const float*)d_in[0];
  const int* ei = (const int*)d_in[1];
  const float* Wl0 = (const float*)d_in[2];
  const float* Wr0 = (const float*)d_in[3];
  const float* b0 = (const float*)d_in[4];
  const float* Wl1 = (const float*)d_in[5];
  const float* Wr1 = (const float*)d_in[6];
  const float* b1 = (const float*)d_in[7];
  const float* Wl2 = (const float*)d_in[8];
  const float* Wr2 = (const float*)d_in[9];
  const float* b2 = (const float*)d_in[10];

  const int N = in_sizes[0] / D;   // 100000
  const int E = in_sizes[1] / 2;   // 1600000
  const int* src = ei;
  const int* dst = ei + E;

  // ---- workspace ----
  const size_t hfBytes = (size_t)N * D * 2;   // 25.6 MB
  char* wsp = (char*)d_ws;
  size_t off = 0;
  unsigned short* xhf   = (unsigned short*)(wsp + off); off += hfBytes;
  unsigned short* agghf = (unsigned short*)(wsp + off); off += hfBytes;
  unsigned short* Wt    = (unsigned short*)(wsp + off); off += ((size_t)3 * 128 * 256 * 2 + 511) & ~511ull;
  int* rowStart  = (int*)(wsp + off); off += ((size_t)(N + 1) * 4 + 511) & ~511ull;
  int* cursor    = (int*)(wsp + off); off += ((size_t)N * 4 + 511) & ~511ull;
  int* blockSums = (int*)(wsp + off); off += 2048;
  int* bucketCursor = (int*)(wsp + off); off += 4096;
  int* csrSrc    = (int*)(wsp + off); off += (size_t)E * 4;
  uint2* pairs   = (uint2*)(wsp + off); off += (size_t)E * 8;   // 12.8 MB

  const int nChunks = (N + CHUNK - 1) / CHUNK;            // 98
  const int nBuck = (N + (1 << BSHIFT) - 1) >> BSHIFT;    // 196

  // ---- JAX partitionable threefry keys on host ----
  unsigned k1a, k1b, k2a, k2b;
  threefry2x32(0u, 42u, 0u, 0u, k1a, k1b);
  threefry2x32(0u, 42u, 0u, 1u, k2a, k2b);

  // ---- CSR build ----
  hipMemsetAsync(cursor, 0, (size_t)N * 4, stream);
  hist_kernel<<<(E + 255) / 256, 256, 0, stream>>>(dst, cursor, E);
  reduce_chunk_kernel<<<nChunks, 256, 0, stream>>>(cursor, blockSums, N);
  scan_block_sums_kernel<<<1, 64, 0, stream>>>(blockSums, nChunks);
  scan_chunk_kernel<<<nChunks, 256, 0, stream>>>(cursor, blockSums, rowStart, cursor, N);
  init_bucket_cursor_kernel<<<(nBuck + 256) / 256, 256, 0, stream>>>(rowStart, bucketCursor, nBuck, N);
  bucket_scatter_kernel<<<(E + 4095) / 4096, 256, 0, stream>>>(src, dst, bucketCursor, pairs, E, nBuck);
  local_fill_kernel<<<nBuck, 256, 0, stream>>>(pairs, rowStart, cursor, csrSrc, N);

  // ---- prep fp16 ----
  convert_feat_kernel<<<(N * D / 4 + 255) / 256, 256, 0, stream>>>(feat, xhf, N * D);
  pack_weights_kernel<<<(3 * 128 * 256 + 255) / 256, 256, 0, stream>>>(
      Wl0, Wr0, Wl1, Wr1, Wl2, Wr2, Wt);

  dim3 blk(256);
  dim3 grdMax((N + 3) / 4);
  dim3 grdGemm((N + 31) / 32);
  float* outF = (float*)d_out;

  // ---- layer 0 ----
  gather_max_f16_kernel<<<grdMax, blk, 0, stream>>>((const uint4*)xhf, rowStart, csrSrc, (uint4*)agghf, N);
  fused_mfma_kernel<<<grdGemm, blk, 0, stream>>>(agghf, xhf, Wt, b0, outF, N, 0, k1a, k1b);

  // ---- layer 1 ----
  gather_max_f16_kernel<<<grdMax, blk, 0, stream>>>((const uint4*)xhf, rowStart, csrSrc, (uint4*)agghf, N);
  fused_mfma_kernel<<<grdGemm, blk, 0, stream>>>(agghf, xhf, Wt + 32768, b1, outF, N, 1, k2a, k2b);

  // ---- layer 2 (fp32 out) ----
  gather_max_f16_kernel<<<grdMax, blk, 0, stream>>>((const uint4*)xhf, rowStart, csrSrc, (uint4*)agghf, N);
  fused_mfma_kernel<<<grdGemm, blk, 0, stream>>>(agghf, xhf, Wt + 65536, b2, outF, N, 2, 0u, 0u);
}